// Round 12
// baseline (57.451 us; speedup 1.0000x reference)
//
#include <hip/hip_runtime.h>
#include <hip/hip_bf16.h>

#define B_  8
#define C_  32
#define H_  128
#define W_  128
#define CO_ 64
#define KK_ 9
#define HW_ (H_*W_)

typedef short s16x8 __attribute__((ext_vector_type(8)));   // 8 bf16 operand
typedef float f32x4 __attribute__((ext_vector_type(4)));   // MFMA accumulator

__device__ __forceinline__ short bf16b(float f) {
    __hip_bfloat16 h = __float2bfloat16(f);
    return __builtin_bit_cast(short, h);
}
__device__ __forceinline__ float bf2f(short s) {
    unsigned u = ((unsigned)(unsigned short)s) << 16;
    return __builtin_bit_cast(float, u);
}

// ---------------------------------------------------------------------------
// Prep (single launch, blockIdx-range dispatch):
//   blocks [0,512):   x f32[img][32][HW] -> xt bf16[img][HW][32] (transpose)
//   blocks [512,584): w_reg -> bf16 A-frag wb[kk][kg][o(64)][j]
//   blocks [584,620): w_off||w_mod||0 -> bf16 A-frag wof[kk][kg][row(32)][j]
// ---------------------------------------------------------------------------
__global__ __launch_bounds__(256) void prep_all(
    const float* __restrict__ x,
    const float* __restrict__ w_reg,
    const float* __restrict__ w_off,
    const float* __restrict__ w_mod,
    short* __restrict__ xt,
    short* __restrict__ wb,
    short* __restrict__ wof)
{
    const int bid = blockIdx.x;
    const int tid = threadIdx.x;
    if (bid < 512) {                       // ---- xt transpose
        const int img = bid & 7;
        const int pix = (bid >> 3) * 256 + tid;
        const float* xb = x + img * (C_ * HW_);
        short v[C_];
        #pragma unroll
        for (int c = 0; c < C_; ++c) v[c] = bf16b(xb[c * HW_ + pix]);
        short* dst = xt + ((size_t)img * HW_ + pix) * C_;
        #pragma unroll
        for (int q = 0; q < 4; ++q)
            *(s16x8*)(dst + q * 8) = *(s16x8*)&v[q * 8];
    } else if (bid < 512 + 72) {           // ---- wb (18432 elements)
        const int idx = (bid - 512) * 256 + tid;
        const int j  = idx & 7;
        const int o  = (idx >> 3) & 63;
        const int kg = (idx >> 9) & 3;
        const int kk = idx >> 11;
        wb[idx] = bf16b(w_reg[(o * C_ + kg * 8 + j) * 9 + kk]);
    } else {                               // ---- wof (9216 elements)
        const int idx = (bid - 584) * 256 + tid;
        const int j   = idx & 7;
        const int row = (idx >> 3) & 31;
        const int kg  = (idx >> 8) & 3;
        const int kk  = idx >> 10;
        const int c   = kg * 8 + j;
        float v = 0.0f;
        if (row < 18)      v = w_off[(row * C_ + c) * 9 + kk];
        else if (row < 27) v = w_mod[((row - 18) * C_ + c) * 9 + kk];
        wof[idx] = bf16b(v);
    }
}

// ---------------------------------------------------------------------------
// Fused: stage-1 conv (MFMA) -> LDS offset exchange -> software-pipelined
// gather + bilinear + MFMA einsum. launch_bounds(256,2): 128-VGPR budget so
// the kk+1 tap loads (4x16B, double-buffered regs) stay in flight under
// kk's bilinear+MFMA. (R10: 36 VGPR -> zero ILP -> 70% stall.)
// ---------------------------------------------------------------------------
__global__ __launch_bounds__(256, 2) void dconv_fused2(
    const short* __restrict__ xt,
    const float* __restrict__ b_off,
    const float* __restrict__ b_mod,
    const short* __restrict__ wof,
    const short* __restrict__ wb,
    float* __restrict__ out)
{
    __shared__ float OFFl[27][72];      // 72 = 64 + pad (bank spread), 7.8 KB

    const int tid  = threadIdx.x;
    const int lane = tid & 63;
    const int wid  = tid >> 6;
    const int fr   = lane & 15;         // pixel within wave slice
    const int fq   = lane >> 4;         // channel group
    const int img  = blockIdx.x & 7;    // image == XCD
    const int hwbase = (blockIdx.x >> 3) * 64 + wid * 16;
    const int hw = hwbase + fr;
    const int h  = hw / W_;
    const int w  = hw % W_;
    const short* xtb = xt + (size_t)img * HW_ * C_;
    const s16x8* wofv = (const s16x8*)wof;
    const s16x8* wbv  = (const s16x8*)wb;
    const int col = wid * 16 + fr;      // my pixel's column in OFFl

    // ---------------- phase 1: offsets/mask via MFMA -----------------------
    {
        f32x4 oa0 = (f32x4){0.f, 0.f, 0.f, 0.f};
        f32x4 oa1 = (f32x4){0.f, 0.f, 0.f, 0.f};
        const s16x8 zf = (s16x8){0,0,0,0,0,0,0,0};

        #pragma unroll
        for (int t = 0; t < 9; ++t) {
            const int yy = h + t / 3 - 1;
            const int xx = w + t % 3 - 1;
            const bool ok = (yy >= 0) & (yy < H_) & (xx >= 0) & (xx < W_);
            const int idx = yy * W_ + xx;
            const s16x8 bfrag = ok ? *(const s16x8*)&xtb[idx * C_ + fq * 8] : zf;
            const s16x8 af0 = wofv[(t * 4 + fq) * 32 + fr];
            const s16x8 af1 = wofv[(t * 4 + fq) * 32 + 16 + fr];
            oa0 = __builtin_amdgcn_mfma_f32_16x16x32_bf16(af0, bfrag, oa0, 0, 0, 0);
            oa1 = __builtin_amdgcn_mfma_f32_16x16x32_bf16(af1, bfrag, oa1, 0, 0, 0);
        }
        // D lane l: row o = ot*16 + fq*4 + i, col = fr -> LDS
        #pragma unroll
        for (int i = 0; i < 4; ++i) {
            const int o = fq * 4 + i;                 // 0..15: offsets
            OFFl[o][col] = fminf(fmaxf(oa0[i] + b_off[o], -32.0f), 32.0f);
        }
        #pragma unroll
        for (int i = 0; i < 4; ++i) {
            const int o = 16 + fq * 4 + i;            // 16,17: off; 18..26: mask
            const float v = oa1[i];
            if (o < 18)
                OFFl[o][col] = fminf(fmaxf(v + b_off[o], -32.0f), 32.0f);
            else if (o < 27)
                OFFl[o][col] = 2.0f / (1.0f + expf(-(v + b_mod[o - 18])));
        }
    }
    __syncthreads();

    // ---------------- phase 2: pipelined gather + bilinear + einsum --------
    const short* xtg = xtb + fq * 8;

    // weights + clamped tap byte-offsets for kernel position kk2
    auto WCALC = [&](int kk2, float& w00, float& w01, float& w10, float& w11,
                     int& a00, int& a01, int& a10, int& a11) {
        const int ky = kk2 / 3, kx = kk2 % 3;
        const float offy = OFFl[2 * kk2 + 0][col];
        const float offx = OFFl[2 * kk2 + 1][col];
        const float m    = OFFl[18 + kk2][col];

        const float py = offy + (float)(h - 1 + ky);
        const float px = offx + (float)(w - 1 + kx);
        const float y0f = floorf(py), x0f = floorf(px);
        const float dy = py - y0f,   dx = px - x0f;
        const int y0 = (int)y0f, x0 = (int)x0f;
        const int y1 = y0 + 1,   x1 = x0 + 1;
        const bool vy0 = (y0 >= 0) & (y0 < H_);
        const bool vy1 = (y1 >= 0) & (y1 < H_);
        const bool vx0 = (x0 >= 0) & (x0 < W_);
        const bool vx1 = (x1 >= 0) & (x1 < W_);
        w00 = (vy0 & vx0) ? (1.0f - dy) * (1.0f - dx) * m : 0.0f;
        w01 = (vy0 & vx1) ? (1.0f - dy) * dx * m         : 0.0f;
        w10 = (vy1 & vx0) ? dy * (1.0f - dx) * m         : 0.0f;
        w11 = (vy1 & vx1) ? dy * dx * m                  : 0.0f;
        const int y0c = min(max(y0, 0), H_ - 1), y1c = min(max(y1, 0), H_ - 1);
        const int x0c = min(max(x0, 0), W_ - 1), x1c = min(max(x1, 0), W_ - 1);
        a00 = (y0c * W_ + x0c) * C_;
        a01 = (y0c * W_ + x1c) * C_;
        a10 = (y1c * W_ + x0c) * C_;
        a11 = (y1c * W_ + x1c) * C_;
    };

    f32x4 acc[4];
    #pragma unroll
    for (int ot = 0; ot < 4; ++ot) acc[ot] = (f32x4){0.f, 0.f, 0.f, 0.f};

    // prologue: weights+loads for kk=0
    float w00, w01, w10, w11;
    int   a00, a01, a10, a11;
    WCALC(0, w00, w01, w10, w11, a00, a01, a10, a11);
    s16x8 t00 = *(const s16x8*)&xtg[a00];
    s16x8 t01 = *(const s16x8*)&xtg[a01];
    s16x8 t10 = *(const s16x8*)&xtg[a10];
    s16x8 t11 = *(const s16x8*)&xtg[a11];

    #pragma unroll
    for (int kk = 0; kk < KK_; ++kk) {
        // issue kk+1's weight calc + tap loads FIRST (hide under kk's work)
        float nw00, nw01, nw10, nw11;
        s16x8 n00, n01, n10, n11;
        if (kk + 1 < KK_) {
            int b00, b01, b10, b11;
            WCALC(kk + 1, nw00, nw01, nw10, nw11, b00, b01, b10, b11);
            n00 = *(const s16x8*)&xtg[b00];
            n01 = *(const s16x8*)&xtg[b01];
            n10 = *(const s16x8*)&xtg[b10];
            n11 = *(const s16x8*)&xtg[b11];
        }

        // bilinear + pack for kk (taps already resident)
        s16x8 bfrag;
        #pragma unroll
        for (int j = 0; j < 8; ++j) {
            const float s = w00 * bf2f(t00[j]) + w01 * bf2f(t01[j])
                          + w10 * bf2f(t10[j]) + w11 * bf2f(t11[j]);
            bfrag[j] = bf16b(s);
        }

        s16x8 af[4];
        #pragma unroll
        for (int ot = 0; ot < 4; ++ot)
            af[ot] = wbv[(kk * 4 + fq) * 64 + ot * 16 + fr];

        #pragma unroll
        for (int ot = 0; ot < 4; ++ot)
            acc[ot] = __builtin_amdgcn_mfma_f32_16x16x32_bf16(
                          af[ot], bfrag, acc[ot], 0, 0, 0);

        if (kk + 1 < KK_) {          // rotate pipeline registers
            t00 = n00; t01 = n01; t10 = n10; t11 = n11;
            w00 = nw00; w01 = nw01; w10 = nw10; w11 = nw11;
        }
    }

    float* outb = out + (size_t)img * (CO_ * HW_) + hwbase + fr;
    #pragma unroll
    for (int ot = 0; ot < 4; ++ot)
        #pragma unroll
        for (int i = 0; i < 4; ++i)
            outb[(ot * 16 + fq * 4 + i) * HW_] = acc[ot][i];
}

// ---------------------------------------------------------------------------
// Fallback (R5 fused kernel) if workspace is too small for the pipeline.
// ---------------------------------------------------------------------------
#define TPF_ 128
#define NTF_ 128
__global__ __launch_bounds__(NTF_, 2) void dconv_fallback(
    const float* __restrict__ x, const float* __restrict__ w_off,
    const float* __restrict__ b_off, const float* __restrict__ w_mod,
    const float* __restrict__ b_mod, const float* __restrict__ w_reg,
    float* __restrict__ out)
{
    __shared__ short Sl[2][4][TPF_][8];
    __shared__ short Wl[2][4][CO_][8];
    const int tid = threadIdx.x;
    const int bidx = blockIdx.x & 7;
    const int hwbase = (blockIdx.x >> 3) * TPF_;
    const int hw = hwbase + tid;
    const int h = hw / W_, w = hw % W_;
    const float* xb = x + bidx * (C_ * HW_);
    float oacc[27];
    #pragma unroll
    for (int j = 0; j < 18; ++j) oacc[j] = b_off[j];
    #pragma unroll
    for (int j = 0; j < 9; ++j)  oacc[18 + j] = b_mod[j];
    for (int c = 0; c < C_; ++c) {
        float xv[9];
        #pragma unroll
        for (int t = 0; t < 9; ++t) {
            const int yy = h + t / 3 - 1, xx = w + t % 3 - 1;
            const bool ok = (yy >= 0) & (yy < H_) & (xx >= 0) & (xx < W_);
            xv[t] = ok ? xb[c * HW_ + yy * W_ + xx] : 0.0f;
        }
        const float* wo = w_off + c * 9;
        #pragma unroll
        for (int j = 0; j < 18; ++j)
            #pragma unroll
            for (int t = 0; t < 9; ++t)
                oacc[j] = fmaf(wo[j * (C_ * 9) + t], xv[t], oacc[j]);
        const float* wm = w_mod + c * 9;
        #pragma unroll
        for (int j = 0; j < 9; ++j)
            #pragma unroll
            for (int t = 0; t < 9; ++t)
                oacc[18 + j] = fmaf(wm[j * (C_ * 9) + t], xv[t], oacc[18 + j]);
    }
    #pragma unroll
    for (int j = 0; j < 18; ++j) oacc[j] = fminf(fmaxf(oacc[j], -32.0f), 32.0f);
    #pragma unroll
    for (int j = 0; j < 9; ++j)  oacc[18 + j] = 2.0f / (1.0f + expf(-oacc[18 + j]));
    auto GATHER = [&](int kk2, float* sarr) {
        const int ky = kk2 / 3, kx = kk2 % 3;
        const float py = oacc[kk2 * 2] + (float)(h - 1 + ky);
        const float px = oacc[kk2 * 2 + 1] + (float)(w - 1 + kx);
        const float m = oacc[18 + kk2];
        const float y0f = floorf(py), x0f = floorf(px);
        const float dy = py - y0f, dx = px - x0f;
        const int y0 = (int)y0f, x0 = (int)x0f, y1 = y0 + 1, x1 = x0 + 1;
        const bool vy0 = (y0 >= 0) & (y0 < H_), vy1 = (y1 >= 0) & (y1 < H_);
        const bool vx0 = (x0 >= 0) & (x0 < W_), vx1 = (x1 >= 0) & (x1 < W_);
        const float wm00 = (vy0 & vx0) ? (1.0f - dy) * (1.0f - dx) * m : 0.0f;
        const float wm01 = (vy0 & vx1) ? (1.0f - dy) * dx * m : 0.0f;
        const float wm10 = (vy1 & vx0) ? dy * (1.0f - dx) * m : 0.0f;
        const float wm11 = (vy1 & vx1) ? dy * dx * m : 0.0f;
        const int y0c = min(max(y0, 0), H_ - 1), y1c = min(max(y1, 0), H_ - 1);
        const int x0c = min(max(x0, 0), W_ - 1), x1c = min(max(x1, 0), W_ - 1);
        const int i00 = y0c * W_ + x0c, i01 = y0c * W_ + x1c;
        const int i10 = y1c * W_ + x0c, i11 = y1c * W_ + x1c;
        #pragma unroll
        for (int c4 = 0; c4 < C_; c4 += 4)
            #pragma unroll
            for (int u = 0; u < 4; ++u) {
                const float* xc = xb + (c4 + u) * HW_;
                sarr[c4 + u] = wm00 * xc[i00] + wm01 * xc[i01]
                             + wm10 * xc[i10] + wm11 * xc[i11];
            }
    };
    auto WSTAGE = [&](int kk2, s16x8* wv) {
        #pragma unroll
        for (int i = 0; i < 2; ++i) {
            const int v = i * NTF_ + tid;
            const int kg = v >> 6, o = v & 63;
            s16x8 t;
            #pragma unroll
            for (int j = 0; j < 8; ++j)
                t[j] = bf16b(w_reg[(o * C_ + kg * 8 + j) * 9 + kk2]);
            wv[i] = t;
        }
    };
    auto PACK = [&](int buf, const float* sarr, const s16x8* wv) {
        #pragma unroll
        for (int kg = 0; kg < 4; ++kg) {
            s16x8 v;
            #pragma unroll
            for (int j = 0; j < 8; ++j) v[j] = bf16b(sarr[kg * 8 + j]);
            *(s16x8*)&Sl[buf][kg][tid][0] = v;
        }
        #pragma unroll
        for (int i = 0; i < 2; ++i) {
            const int v = i * NTF_ + tid;
            const int kg = v >> 6, o = v & 63;
            *(s16x8*)&Wl[buf][kg][o][0] = wv[i];
        }
    };
    { float s0[C_]; s16x8 wv0[2]; GATHER(0, s0); WSTAGE(0, wv0); PACK(0, s0, wv0); }
    __syncthreads();
    const int lane = tid & 63, wid = tid >> 6, fr = lane & 15, fq = lane >> 4;
    f32x4 acc[4][4];
    #pragma unroll
    for (int ot = 0; ot < 4; ++ot)
        #pragma unroll
        for (int pt = 0; pt < 4; ++pt) acc[ot][pt] = (f32x4){0.f,0.f,0.f,0.f};
    #pragma unroll
    for (int kk = 0; kk < KK_; ++kk) {
        const int cur = kk & 1, nxt = cur ^ 1;
        s16x8 af[4], bfg[4];
        #pragma unroll
        for (int ot = 0; ot < 4; ++ot) af[ot] = *(const s16x8*)&Wl[cur][fq][ot*16+fr][0];
        #pragma unroll
        for (int pt = 0; pt < 4; ++pt) bfg[pt] = *(const s16x8*)&Sl[cur][fq][wid*64+pt*16+fr][0];
        float sn[C_]; s16x8 wvn[2];
        if (kk + 1 < KK_) { GATHER(kk + 1, sn); WSTAGE(kk + 1, wvn); }
        #pragma unroll
        for (int ot = 0; ot < 4; ++ot)
            #pragma unroll
            for (int pt = 0; pt < 4; ++pt)
                acc[ot][pt] = __builtin_amdgcn_mfma_f32_16x16x32_bf16(af[ot], bfg[pt], acc[ot][pt], 0, 0, 0);
        if (kk + 1 < KK_) { PACK(nxt, sn, wvn); __syncthreads(); }
    }
    float* outb = out + (size_t)bidx * (CO_ * HW_) + hwbase;
    #pragma unroll
    for (int ot = 0; ot < 4; ++ot)
        #pragma unroll
        for (int j = 0; j < 4; ++j) {
            const int o = ot * 16 + fq * 4 + j;
            float* row = outb + o * HW_ + wid * 64 + fr;
            #pragma unroll
            for (int pt = 0; pt < 4; ++pt) row[pt * 16] = acc[ot][pt][j];
        }
}

extern "C" void kernel_launch(void* const* d_in, const int* in_sizes, int n_in,
                              void* d_out, int out_size, void* d_ws, size_t ws_size,
                              hipStream_t stream) {
    const float* x     = (const float*)d_in[0];
    const float* w_off = (const float*)d_in[1];
    const float* b_off = (const float*)d_in[2];
    const float* w_mod = (const float*)d_in[3];
    const float* b_mod = (const float*)d_in[4];
    const float* w_reg = (const float*)d_in[5];
    float* out = (float*)d_out;

    const size_t WOF_OFFS = 36864;                                  // after wb
    const size_t XT_OFFS  = 65536;
    const size_t XT_BYTES = (size_t)B_ * HW_ * C_ * sizeof(short);  // 8.4 MB

    if (ws_size >= XT_OFFS + XT_BYTES) {
        short* wb  = (short*)d_ws;
        short* wof = (short*)((char*)d_ws + WOF_OFFS);
        short* xtp = (short*)((char*)d_ws + XT_OFFS);
        prep_all<<<620, 256, 0, stream>>>(x, w_reg, w_off, w_mod, xtp, wb, wof);
        dconv_fused2<<<B_ * HW_ / 64, 256, 0, stream>>>(xtp, b_off, b_mod,
                                                        wof, wb, out);
    } else {
        dconv_fallback<<<B_ * HW_ / TPF_, NTF_, 0, stream>>>(
            x, w_off, b_off, w_mod, b_mod, w_reg, out);
    }
}

// Round 13
// 48.354 us; speedup vs baseline: 1.1881x; 1.1881x over previous
//
#include <hip/hip_runtime.h>
#include <hip/hip_bf16.h>

#define B_  8
#define C_  32
#define H_  128
#define W_  128
#define CO_ 64
#define KK_ 9
#define HW_ (H_*W_)

typedef short s16x8 __attribute__((ext_vector_type(8)));   // 8 bf16 operand
typedef float f32x4 __attribute__((ext_vector_type(4)));   // MFMA accumulator

__device__ __forceinline__ short bf16b(float f) {
    __hip_bfloat16 h = __float2bfloat16(f);
    return __builtin_bit_cast(short, h);
}
__device__ __forceinline__ float bf2f(short s) {
    unsigned u = ((unsigned)(unsigned short)s) << 16;
    return __builtin_bit_cast(float, u);
}

// ---------------------------------------------------------------------------
// Prep (single launch, blockIdx-range dispatch):
//   blocks [0,512):   x f32[img][32][HW] -> xt bf16[img][HW][32] (transpose)
//   blocks [512,584): w_reg -> bf16 A-frag wb[kk][kg][o(64)][j]
//   blocks [584,620): w_off||w_mod||0 -> bf16 A-frag wof[kk][kg][row(32)][j]
// ---------------------------------------------------------------------------
__global__ __launch_bounds__(256) void prep_all(
    const float* __restrict__ x,
    const float* __restrict__ w_reg,
    const float* __restrict__ w_off,
    const float* __restrict__ w_mod,
    short* __restrict__ xt,
    short* __restrict__ wb,
    short* __restrict__ wof)
{
    const int bid = blockIdx.x;
    const int tid = threadIdx.x;
    if (bid < 512) {                       // ---- xt transpose
        const int img = bid & 7;
        const int pix = (bid >> 3) * 256 + tid;
        const float* xb = x + img * (C_ * HW_);
        short v[C_];
        #pragma unroll
        for (int c = 0; c < C_; ++c) v[c] = bf16b(xb[c * HW_ + pix]);
        short* dst = xt + ((size_t)img * HW_ + pix) * C_;
        #pragma unroll
        for (int q = 0; q < 4; ++q)
            *(s16x8*)(dst + q * 8) = *(s16x8*)&v[q * 8];
    } else if (bid < 512 + 72) {           // ---- wb (18432 elements)
        const int idx = (bid - 512) * 256 + tid;
        const int j  = idx & 7;
        const int o  = (idx >> 3) & 63;
        const int kg = (idx >> 9) & 3;
        const int kk = idx >> 11;
        wb[idx] = bf16b(w_reg[(o * C_ + kg * 8 + j) * 9 + kk]);
    } else {                               // ---- wof (9216 elements)
        const int idx = (bid - 584) * 256 + tid;
        const int j   = idx & 7;
        const int row = (idx >> 3) & 31;
        const int kg  = (idx >> 8) & 3;
        const int kk  = idx >> 10;
        const int c   = kg * 8 + j;
        float v = 0.0f;
        if (row < 18)      v = w_off[(row * C_ + c) * 9 + kk];
        else if (row < 27) v = w_mod[((row - 18) * C_ + c) * 9 + kk];
        wof[idx] = bf16b(v);
    }
}

// ---------------------------------------------------------------------------
// Fused: stage-1 conv (MFMA) + wb->LDS staging -> barrier -> gather +
// bilinear + MFMA einsum with A-frags from LDS (ds_read, off the TA port).
// R11 analysis: 36 wb global loads/wave/phase2 were half the TA stream;
// moving them to the (idle) LDS pipe halves TA instruction pressure.
// wbl stride = 65 vectors per (kk,fq) group -> bank spread for ds_read_b128.
// ---------------------------------------------------------------------------
__global__ __launch_bounds__(256, 2) void dconv_fused2(
    const short* __restrict__ xt,
    const float* __restrict__ b_off,
    const float* __restrict__ b_mod,
    const short* __restrict__ wof,
    const short* __restrict__ wb,
    float* __restrict__ out)
{
    __shared__ float OFFl[27][72];             // 7.8 KB
    __shared__ short wbl[(KK_ * 4 * 65) * 8];  // 36.6 KB, padded stride 65

    const int tid  = threadIdx.x;
    const int lane = tid & 63;
    const int wid  = tid >> 6;
    const int fr   = lane & 15;         // pixel within wave slice
    const int fq   = lane >> 4;         // channel group
    const int img  = blockIdx.x & 7;    // image == XCD
    const int hwbase = (blockIdx.x >> 3) * 64 + wid * 16;
    const int hw = hwbase + fr;
    const int h  = hw / W_;
    const int w  = hw % W_;
    const short* xtb = xt + (size_t)img * HW_ * C_;
    const s16x8* wofv = (const s16x8*)wof;
    const int col = wid * 16 + fr;      // my pixel's column in OFFl

    // ---- stage wb -> LDS (overlaps phase 1; barrier below covers it) ------
    {
        const s16x8* wbg = (const s16x8*)wb;
        s16x8* wblv = (s16x8*)wbl;
        #pragma unroll
        for (int i = 0; i < 9; ++i) {
            const int v = tid + i * 256;          // 0..2303
            const int kf = v >> 6, slot = v & 63; // kf = kk*4+fq
            wblv[kf * 65 + slot] = wbg[v];
        }
    }

    // ---------------- phase 1: offsets/mask via MFMA -----------------------
    {
        f32x4 oa0 = (f32x4){0.f, 0.f, 0.f, 0.f};
        f32x4 oa1 = (f32x4){0.f, 0.f, 0.f, 0.f};
        const s16x8 zf = (s16x8){0,0,0,0,0,0,0,0};

        #pragma unroll
        for (int t = 0; t < 9; ++t) {
            const int yy = h + t / 3 - 1;
            const int xx = w + t % 3 - 1;
            const bool ok = (yy >= 0) & (yy < H_) & (xx >= 0) & (xx < W_);
            const int idx = yy * W_ + xx;
            const s16x8 bfrag = ok ? *(const s16x8*)&xtb[idx * C_ + fq * 8] : zf;
            const s16x8 af0 = wofv[(t * 4 + fq) * 32 + fr];
            const s16x8 af1 = wofv[(t * 4 + fq) * 32 + 16 + fr];
            oa0 = __builtin_amdgcn_mfma_f32_16x16x32_bf16(af0, bfrag, oa0, 0, 0, 0);
            oa1 = __builtin_amdgcn_mfma_f32_16x16x32_bf16(af1, bfrag, oa1, 0, 0, 0);
        }
        // D lane l: row o = ot*16 + fq*4 + i, col = fr -> LDS
        #pragma unroll
        for (int i = 0; i < 4; ++i) {
            const int o = fq * 4 + i;                 // 0..15: offsets
            OFFl[o][col] = fminf(fmaxf(oa0[i] + b_off[o], -32.0f), 32.0f);
        }
        #pragma unroll
        for (int i = 0; i < 4; ++i) {
            const int o = 16 + fq * 4 + i;            // 16,17: off; 18..26: mask
            const float v = oa1[i];
            if (o < 18)
                OFFl[o][col] = fminf(fmaxf(v + b_off[o], -32.0f), 32.0f);
            else if (o < 27)
                OFFl[o][col] = 2.0f / (1.0f + expf(-(v + b_mod[o - 18])));
        }
    }
    __syncthreads();

    // ---------------- phase 2: pipelined gather + bilinear + einsum --------
    const short* xtg = xtb + fq * 8;
    const s16x8* wblv = (const s16x8*)wbl;

    auto WCALC = [&](int kk2, float& w00, float& w01, float& w10, float& w11,
                     int& a00, int& a01, int& a10, int& a11) {
        const int ky = kk2 / 3, kx = kk2 % 3;
        const float offy = OFFl[2 * kk2 + 0][col];
        const float offx = OFFl[2 * kk2 + 1][col];
        const float m    = OFFl[18 + kk2][col];

        const float py = offy + (float)(h - 1 + ky);
        const float px = offx + (float)(w - 1 + kx);
        const float y0f = floorf(py), x0f = floorf(px);
        const float dy = py - y0f,   dx = px - x0f;
        const int y0 = (int)y0f, x0 = (int)x0f;
        const int y1 = y0 + 1,   x1 = x0 + 1;
        const bool vy0 = (y0 >= 0) & (y0 < H_);
        const bool vy1 = (y1 >= 0) & (y1 < H_);
        const bool vx0 = (x0 >= 0) & (x0 < W_);
        const bool vx1 = (x1 >= 0) & (x1 < W_);
        w00 = (vy0 & vx0) ? (1.0f - dy) * (1.0f - dx) * m : 0.0f;
        w01 = (vy0 & vx1) ? (1.0f - dy) * dx * m         : 0.0f;
        w10 = (vy1 & vx0) ? dy * (1.0f - dx) * m         : 0.0f;
        w11 = (vy1 & vx1) ? dy * dx * m                  : 0.0f;
        const int y0c = min(max(y0, 0), H_ - 1), y1c = min(max(y1, 0), H_ - 1);
        const int x0c = min(max(x0, 0), W_ - 1), x1c = min(max(x1, 0), W_ - 1);
        a00 = (y0c * W_ + x0c) * C_;
        a01 = (y0c * W_ + x1c) * C_;
        a10 = (y1c * W_ + x0c) * C_;
        a11 = (y1c * W_ + x1c) * C_;
    };

    f32x4 acc[4];
    #pragma unroll
    for (int ot = 0; ot < 4; ++ot) acc[ot] = (f32x4){0.f, 0.f, 0.f, 0.f};

    // prologue: weights+loads for kk=0
    float w00, w01, w10, w11;
    int   a00, a01, a10, a11;
    WCALC(0, w00, w01, w10, w11, a00, a01, a10, a11);
    s16x8 t00 = *(const s16x8*)&xtg[a00];
    s16x8 t01 = *(const s16x8*)&xtg[a01];
    s16x8 t10 = *(const s16x8*)&xtg[a10];
    s16x8 t11 = *(const s16x8*)&xtg[a11];

    #pragma unroll
    for (int kk = 0; kk < KK_; ++kk) {
        // issue kk+1's weight calc + tap loads first (hide under kk's work)
        float nw00, nw01, nw10, nw11;
        s16x8 n00, n01, n10, n11;
        if (kk + 1 < KK_) {
            int b00, b01, b10, b11;
            WCALC(kk + 1, nw00, nw01, nw10, nw11, b00, b01, b10, b11);
            n00 = *(const s16x8*)&xtg[b00];
            n01 = *(const s16x8*)&xtg[b01];
            n10 = *(const s16x8*)&xtg[b10];
            n11 = *(const s16x8*)&xtg[b11];
        }

        // bilinear + pack for kk (taps already resident)
        s16x8 bfrag;
        #pragma unroll
        for (int j = 0; j < 8; ++j) {
            const float s = w00 * bf2f(t00[j]) + w01 * bf2f(t01[j])
                          + w10 * bf2f(t10[j]) + w11 * bf2f(t11[j]);
            bfrag[j] = bf16b(s);
        }

        // A-fragments from LDS (ds_read_b128, padded stride -> bank spread)
        s16x8 af[4];
        #pragma unroll
        for (int ot = 0; ot < 4; ++ot)
            af[ot] = wblv[(kk * 4 + fq) * 65 + ot * 16 + fr];

        #pragma unroll
        for (int ot = 0; ot < 4; ++ot)
            acc[ot] = __builtin_amdgcn_mfma_f32_16x16x32_bf16(
                          af[ot], bfrag, acc[ot], 0, 0, 0);

        if (kk + 1 < KK_) {          // rotate pipeline registers
            t00 = n00; t01 = n01; t10 = n10; t11 = n11;
            w00 = nw00; w01 = nw01; w10 = nw10; w11 = nw11;
        }
    }

    float* outb = out + (size_t)img * (CO_ * HW_) + hwbase + fr;
    #pragma unroll
    for (int ot = 0; ot < 4; ++ot)
        #pragma unroll
        for (int i = 0; i < 4; ++i)
            outb[(ot * 16 + fq * 4 + i) * HW_] = acc[ot][i];
}

// ---------------------------------------------------------------------------
// Fallback (R5 fused kernel) if workspace is too small for the pipeline.
// ---------------------------------------------------------------------------
#define TPF_ 128
#define NTF_ 128
__global__ __launch_bounds__(NTF_, 2) void dconv_fallback(
    const float* __restrict__ x, const float* __restrict__ w_off,
    const float* __restrict__ b_off, const float* __restrict__ w_mod,
    const float* __restrict__ b_mod, const float* __restrict__ w_reg,
    float* __restrict__ out)
{
    __shared__ short Sl[2][4][TPF_][8];
    __shared__ short Wl[2][4][CO_][8];
    const int tid = threadIdx.x;
    const int bidx = blockIdx.x & 7;
    const int hwbase = (blockIdx.x >> 3) * TPF_;
    const int hw = hwbase + tid;
    const int h = hw / W_, w = hw % W_;
    const float* xb = x + bidx * (C_ * HW_);
    float oacc[27];
    #pragma unroll
    for (int j = 0; j < 18; ++j) oacc[j] = b_off[j];
    #pragma unroll
    for (int j = 0; j < 9; ++j)  oacc[18 + j] = b_mod[j];
    for (int c = 0; c < C_; ++c) {
        float xv[9];
        #pragma unroll
        for (int t = 0; t < 9; ++t) {
            const int yy = h + t / 3 - 1, xx = w + t % 3 - 1;
            const bool ok = (yy >= 0) & (yy < H_) & (xx >= 0) & (xx < W_);
            xv[t] = ok ? xb[c * HW_ + yy * W_ + xx] : 0.0f;
        }
        const float* wo = w_off + c * 9;
        #pragma unroll
        for (int j = 0; j < 18; ++j)
            #pragma unroll
            for (int t = 0; t < 9; ++t)
                oacc[j] = fmaf(wo[j * (C_ * 9) + t], xv[t], oacc[j]);
        const float* wm = w_mod + c * 9;
        #pragma unroll
        for (int j = 0; j < 9; ++j)
            #pragma unroll
            for (int t = 0; t < 9; ++t)
                oacc[18 + j] = fmaf(wm[j * (C_ * 9) + t], xv[t], oacc[18 + j]);
    }
    #pragma unroll
    for (int j = 0; j < 18; ++j) oacc[j] = fminf(fmaxf(oacc[j], -32.0f), 32.0f);
    #pragma unroll
    for (int j = 0; j < 9; ++j)  oacc[18 + j] = 2.0f / (1.0f + expf(-oacc[18 + j]));
    auto GATHER = [&](int kk2, float* sarr) {
        const int ky = kk2 / 3, kx = kk2 % 3;
        const float py = oacc[kk2 * 2] + (float)(h - 1 + ky);
        const float px = oacc[kk2 * 2 + 1] + (float)(w - 1 + kx);
        const float m = oacc[18 + kk2];
        const float y0f = floorf(py), x0f = floorf(px);
        const float dy = py - y0f, dx = px - x0f;
        const int y0 = (int)y0f, x0 = (int)x0f, y1 = y0 + 1, x1 = x0 + 1;
        const bool vy0 = (y0 >= 0) & (y0 < H_), vy1 = (y1 >= 0) & (y1 < H_);
        const bool vx0 = (x0 >= 0) & (x0 < W_), vx1 = (x1 >= 0) & (x1 < W_);
        const float wm00 = (vy0 & vx0) ? (1.0f - dy) * (1.0f - dx) * m : 0.0f;
        const float wm01 = (vy0 & vx1) ? (1.0f - dy) * dx * m : 0.0f;
        const float wm10 = (vy1 & vx0) ? dy * (1.0f - dx) * m : 0.0f;
        const float wm11 = (vy1 & vx1) ? dy * dx * m : 0.0f;
        const int y0c = min(max(y0, 0), H_ - 1), y1c = min(max(y1, 0), H_ - 1);
        const int x0c = min(max(x0, 0), W_ - 1), x1c = min(max(x1, 0), W_ - 1);
        const int i00 = y0c * W_ + x0c, i01 = y0c * W_ + x1c;
        const int i10 = y1c * W_ + x0c, i11 = y1c * W_ + x1c;
        #pragma unroll
        for (int c4 = 0; c4 < C_; c4 += 4)
            #pragma unroll
            for (int u = 0; u < 4; ++u) {
                const float* xc = xb + (c4 + u) * HW_;
                sarr[c4 + u] = wm00 * xc[i00] + wm01 * xc[i01]
                             + wm10 * xc[i10] + wm11 * xc[i11];
            }
    };
    auto WSTAGE = [&](int kk2, s16x8* wv) {
        #pragma unroll
        for (int i = 0; i < 2; ++i) {
            const int v = i * NTF_ + tid;
            const int kg = v >> 6, o = v & 63;
            s16x8 t;
            #pragma unroll
            for (int j = 0; j < 8; ++j)
                t[j] = bf16b(w_reg[(o * C_ + kg * 8 + j) * 9 + kk2]);
            wv[i] = t;
        }
    };
    auto PACK = [&](int buf, const float* sarr, const s16x8* wv) {
        #pragma unroll
        for (int kg = 0; kg < 4; ++kg) {
            s16x8 v;
            #pragma unroll
            for (int j = 0; j < 8; ++j) v[j] = bf16b(sarr[kg * 8 + j]);
            *(s16x8*)&Sl[buf][kg][tid][0] = v;
        }
        #pragma unroll
        for (int i = 0; i < 2; ++i) {
            const int v = i * NTF_ + tid;
            const int kg = v >> 6, o = v & 63;
            *(s16x8*)&Wl[buf][kg][o][0] = wv[i];
        }
    };
    { float s0[C_]; s16x8 wv0[2]; GATHER(0, s0); WSTAGE(0, wv0); PACK(0, s0, wv0); }
    __syncthreads();
    const int lane = tid & 63, wid = tid >> 6, fr = lane & 15, fq = lane >> 4;
    f32x4 acc[4][4];
    #pragma unroll
    for (int ot = 0; ot < 4; ++ot)
        #pragma unroll
        for (int pt = 0; pt < 4; ++pt) acc[ot][pt] = (f32x4){0.f,0.f,0.f,0.f};
    #pragma unroll
    for (int kk = 0; kk < KK_; ++kk) {
        const int cur = kk & 1, nxt = cur ^ 1;
        s16x8 af[4], bfg[4];
        #pragma unroll
        for (int ot = 0; ot < 4; ++ot) af[ot] = *(const s16x8*)&Wl[cur][fq][ot*16+fr][0];
        #pragma unroll
        for (int pt = 0; pt < 4; ++pt) bfg[pt] = *(const s16x8*)&Sl[cur][fq][wid*64+pt*16+fr][0];
        float sn[C_]; s16x8 wvn[2];
        if (kk + 1 < KK_) { GATHER(kk + 1, sn); WSTAGE(kk + 1, wvn); }
        #pragma unroll
        for (int ot = 0; ot < 4; ++ot)
            #pragma unroll
            for (int pt = 0; pt < 4; ++pt)
                acc[ot][pt] = __builtin_amdgcn_mfma_f32_16x16x32_bf16(af[ot], bfg[pt], acc[ot][pt], 0, 0, 0);
        if (kk + 1 < KK_) { PACK(nxt, sn, wvn); __syncthreads(); }
    }
    float* outb = out + (size_t)bidx * (CO_ * HW_) + hwbase;
    #pragma unroll
    for (int ot = 0; ot < 4; ++ot)
        #pragma unroll
        for (int j = 0; j < 4; ++j) {
            const int o = ot * 16 + fq * 4 + j;
            float* row = outb + o * HW_ + wid * 64 + fr;
            #pragma unroll
            for (int pt = 0; pt < 4; ++pt) row[pt * 16] = acc[ot][pt][j];
        }
}

extern "C" void kernel_launch(void* const* d_in, const int* in_sizes, int n_in,
                              void* d_out, int out_size, void* d_ws, size_t ws_size,
                              hipStream_t stream) {
    const float* x     = (const float*)d_in[0];
    const float* w_off = (const float*)d_in[1];
    const float* b_off = (const float*)d_in[2];
    const float* w_mod = (const float*)d_in[3];
    const float* b_mod = (const float*)d_in[4];
    const float* w_reg = (const float*)d_in[5];
    float* out = (float*)d_out;

    const size_t WOF_OFFS = 36864;                                  // after wb
    const size_t XT_OFFS  = 65536;
    const size_t XT_BYTES = (size_t)B_ * HW_ * C_ * sizeof(short);  // 8.4 MB

    if (ws_size >= XT_OFFS + XT_BYTES) {
        short* wb  = (short*)d_ws;
        short* wof = (short*)((char*)d_ws + WOF_OFFS);
        short* xtp = (short*)((char*)d_ws + XT_OFFS);
        prep_all<<<620, 256, 0, stream>>>(x, w_reg, w_off, w_mod, xtp, wb, wof);
        dconv_fused2<<<B_ * HW_ / 64, 256, 0, stream>>>(xtp, b_off, b_mod,
                                                        wof, wb, out);
    } else {
        dconv_fallback<<<B_ * HW_ / TPF_, NTF_, 0, stream>>>(
            x, w_off, b_off, w_mod, b_mod, w_reg, out);
    }
}

// Round 14
// 47.175 us; speedup vs baseline: 1.2178x; 1.0250x over previous
//
#include <hip/hip_runtime.h>
#include <hip/hip_bf16.h>

#define B_  8
#define C_  32
#define H_  128
#define W_  128
#define CO_ 64
#define KK_ 9
#define HW_ (H_*W_)

typedef short s16x8 __attribute__((ext_vector_type(8)));   // 8 bf16 operand
typedef float f32x4 __attribute__((ext_vector_type(4)));   // MFMA accumulator

__device__ __forceinline__ short bf16b(float f) {
    __hip_bfloat16 h = __float2bfloat16(f);
    return __builtin_bit_cast(short, h);
}
__device__ __forceinline__ float bf2f(short s) {
    unsigned u = ((unsigned)(unsigned short)s) << 16;
    return __builtin_bit_cast(float, u);
}

// ---------------------------------------------------------------------------
// Prep (single launch, blockIdx-range dispatch):
//   blocks [0,512):   x f32[img][32][HW] -> xt bf16[img][HW][32] (transpose)
//   blocks [512,584): w_reg -> bf16 A-frag wb[kk][kg][o(64)][j]
//   blocks [584,620): w_off||w_mod||0 -> bf16 A-frag wof[kk][kg][row(32)][j]
// ---------------------------------------------------------------------------
__global__ __launch_bounds__(256) void prep_all(
    const float* __restrict__ x,
    const float* __restrict__ w_reg,
    const float* __restrict__ w_off,
    const float* __restrict__ w_mod,
    short* __restrict__ xt,
    short* __restrict__ wb,
    short* __restrict__ wof)
{
    const int bid = blockIdx.x;
    const int tid = threadIdx.x;
    if (bid < 512) {                       // ---- xt transpose
        const int img = bid & 7;
        const int pix = (bid >> 3) * 256 + tid;
        const float* xb = x + img * (C_ * HW_);
        short v[C_];
        #pragma unroll
        for (int c = 0; c < C_; ++c) v[c] = bf16b(xb[c * HW_ + pix]);
        short* dst = xt + ((size_t)img * HW_ + pix) * C_;
        #pragma unroll
        for (int q = 0; q < 4; ++q)
            *(s16x8*)(dst + q * 8) = *(s16x8*)&v[q * 8];
    } else if (bid < 512 + 72) {           // ---- wb (18432 elements)
        const int idx = (bid - 512) * 256 + tid;
        const int j  = idx & 7;
        const int o  = (idx >> 3) & 63;
        const int kg = (idx >> 9) & 3;
        const int kk = idx >> 11;
        wb[idx] = bf16b(w_reg[(o * C_ + kg * 8 + j) * 9 + kk]);
    } else {                               // ---- wof (9216 elements)
        const int idx = (bid - 584) * 256 + tid;
        const int j   = idx & 7;
        const int row = (idx >> 3) & 31;
        const int kg  = (idx >> 8) & 3;
        const int kk  = idx >> 10;
        const int c   = kg * 8 + j;
        float v = 0.0f;
        if (row < 18)      v = w_off[(row * C_ + c) * 9 + kk];
        else if (row < 27) v = w_mod[((row - 18) * C_ + c) * 9 + kk];
        wof[idx] = bf16b(v);
    }
}

// ---------------------------------------------------------------------------
// Fused, 512-thread blocks (8 waves, 128 px): the 36.6 KB wbl LDS copy is
// amortized over 2x the waves -> ~24 waves/CU (R12: 45.6KB/4-wave block
// capped occupancy at 23%). Phase 1: offsets via MFMA. Phase 2: gather +
// bilinear + einsum, A-frags via ds_read.
// ---------------------------------------------------------------------------
__global__ __launch_bounds__(512, 4) void dconv_fused2(
    const short* __restrict__ xt,
    const float* __restrict__ b_off,
    const float* __restrict__ b_mod,
    const short* __restrict__ wof,
    const short* __restrict__ wb,
    float* __restrict__ out)
{
    __shared__ float OFFl[27][136];            // 128 cols + pad, 14.7 KB
    __shared__ short wbl[(KK_ * 4 * 65) * 8];  // 36.6 KB, padded stride 65

    const int tid  = threadIdx.x;
    const int lane = tid & 63;
    const int wid  = tid >> 6;          // 8 waves
    const int fr   = lane & 15;         // pixel within wave slice
    const int fq   = lane >> 4;         // channel group
    const int img  = blockIdx.x & 7;    // image == XCD
    const int hwbase = (blockIdx.x >> 3) * 128 + wid * 16;
    const int hw = hwbase + fr;
    const int h  = hw / W_;
    const int w  = hw % W_;
    const short* xtb = xt + (size_t)img * HW_ * C_;
    const s16x8* wofv = (const s16x8*)wof;
    const int col = wid * 16 + fr;      // my pixel's column in OFFl (0..127)

    // ---- stage wb -> LDS (overlaps phase 1; barrier below covers it) ------
    {
        const s16x8* wbg = (const s16x8*)wb;
        s16x8* wblv = (s16x8*)wbl;
        #pragma unroll
        for (int i = 0; i < 5; ++i) {
            const int v = tid + i * 512;          // 0..2303
            if (v < KK_ * 4 * 64) {
                const int kf = v >> 6, slot = v & 63; // kf = kk*4+fq
                wblv[kf * 65 + slot] = wbg[v];
            }
        }
    }

    // ---------------- phase 1: offsets/mask via MFMA -----------------------
    {
        f32x4 oa0 = (f32x4){0.f, 0.f, 0.f, 0.f};
        f32x4 oa1 = (f32x4){0.f, 0.f, 0.f, 0.f};
        const s16x8 zf = (s16x8){0,0,0,0,0,0,0,0};

        #pragma unroll
        for (int t = 0; t < 9; ++t) {
            const int yy = h + t / 3 - 1;
            const int xx = w + t % 3 - 1;
            const bool ok = (yy >= 0) & (yy < H_) & (xx >= 0) & (xx < W_);
            const int idx = yy * W_ + xx;
            const s16x8 bfrag = ok ? *(const s16x8*)&xtb[idx * C_ + fq * 8] : zf;
            const s16x8 af0 = wofv[(t * 4 + fq) * 32 + fr];
            const s16x8 af1 = wofv[(t * 4 + fq) * 32 + 16 + fr];
            oa0 = __builtin_amdgcn_mfma_f32_16x16x32_bf16(af0, bfrag, oa0, 0, 0, 0);
            oa1 = __builtin_amdgcn_mfma_f32_16x16x32_bf16(af1, bfrag, oa1, 0, 0, 0);
        }
        // D lane l: row o = ot*16 + fq*4 + i, col = fr -> LDS
        #pragma unroll
        for (int i = 0; i < 4; ++i) {
            const int o = fq * 4 + i;                 // 0..15: offsets
            OFFl[o][col] = fminf(fmaxf(oa0[i] + b_off[o], -32.0f), 32.0f);
        }
        #pragma unroll
        for (int i = 0; i < 4; ++i) {
            const int o = 16 + fq * 4 + i;            // 16,17: off; 18..26: mask
            const float v = oa1[i];
            if (o < 18)
                OFFl[o][col] = fminf(fmaxf(v + b_off[o], -32.0f), 32.0f);
            else if (o < 27)
                OFFl[o][col] = 2.0f / (1.0f + expf(-(v + b_mod[o - 18])));
        }
    }
    __syncthreads();

    // ---------------- phase 2: gather + bilinear + einsum ------------------
    const short* xtg = xtb + fq * 8;
    const s16x8* wblv = (const s16x8*)wbl;

    auto WCALC = [&](int kk2, float& w00, float& w01, float& w10, float& w11,
                     int& a00, int& a01, int& a10, int& a11) {
        const int ky = kk2 / 3, kx = kk2 % 3;
        const float offy = OFFl[2 * kk2 + 0][col];
        const float offx = OFFl[2 * kk2 + 1][col];
        const float m    = OFFl[18 + kk2][col];

        const float py = offy + (float)(h - 1 + ky);
        const float px = offx + (float)(w - 1 + kx);
        const float y0f = floorf(py), x0f = floorf(px);
        const float dy = py - y0f,   dx = px - x0f;
        const int y0 = (int)y0f, x0 = (int)x0f;
        const int y1 = y0 + 1,   x1 = x0 + 1;
        const bool vy0 = (y0 >= 0) & (y0 < H_);
        const bool vy1 = (y1 >= 0) & (y1 < H_);
        const bool vx0 = (x0 >= 0) & (x0 < W_);
        const bool vx1 = (x1 >= 0) & (x1 < W_);
        w00 = (vy0 & vx0) ? (1.0f - dy) * (1.0f - dx) * m : 0.0f;
        w01 = (vy0 & vx1) ? (1.0f - dy) * dx * m         : 0.0f;
        w10 = (vy1 & vx0) ? dy * (1.0f - dx) * m         : 0.0f;
        w11 = (vy1 & vx1) ? dy * dx * m                  : 0.0f;
        const int y0c = min(max(y0, 0), H_ - 1), y1c = min(max(y1, 0), H_ - 1);
        const int x0c = min(max(x0, 0), W_ - 1), x1c = min(max(x1, 0), W_ - 1);
        a00 = (y0c * W_ + x0c) * C_;
        a01 = (y0c * W_ + x1c) * C_;
        a10 = (y1c * W_ + x0c) * C_;
        a11 = (y1c * W_ + x1c) * C_;
    };

    f32x4 acc[4];
    #pragma unroll
    for (int ot = 0; ot < 4; ++ot) acc[ot] = (f32x4){0.f, 0.f, 0.f, 0.f};

    // prologue: weights+loads for kk=0
    float w00, w01, w10, w11;
    int   a00, a01, a10, a11;
    WCALC(0, w00, w01, w10, w11, a00, a01, a10, a11);
    s16x8 t00 = *(const s16x8*)&xtg[a00];
    s16x8 t01 = *(const s16x8*)&xtg[a01];
    s16x8 t10 = *(const s16x8*)&xtg[a10];
    s16x8 t11 = *(const s16x8*)&xtg[a11];

    #pragma unroll
    for (int kk = 0; kk < KK_; ++kk) {
        // issue kk+1's weight calc + tap loads first (hide under kk's work)
        float nw00, nw01, nw10, nw11;
        s16x8 n00, n01, n10, n11;
        if (kk + 1 < KK_) {
            int b00, b01, b10, b11;
            WCALC(kk + 1, nw00, nw01, nw10, nw11, b00, b01, b10, b11);
            n00 = *(const s16x8*)&xtg[b00];
            n01 = *(const s16x8*)&xtg[b01];
            n10 = *(const s16x8*)&xtg[b10];
            n11 = *(const s16x8*)&xtg[b11];
        }

        // bilinear + pack for kk (taps already resident)
        s16x8 bfrag;
        #pragma unroll
        for (int j = 0; j < 8; ++j) {
            const float s = w00 * bf2f(t00[j]) + w01 * bf2f(t01[j])
                          + w10 * bf2f(t10[j]) + w11 * bf2f(t11[j]);
            bfrag[j] = bf16b(s);
        }

        // A-fragments from LDS (ds_read_b128)
        s16x8 af[4];
        #pragma unroll
        for (int ot = 0; ot < 4; ++ot)
            af[ot] = wblv[(kk * 4 + fq) * 65 + ot * 16 + fr];

        #pragma unroll
        for (int ot = 0; ot < 4; ++ot)
            acc[ot] = __builtin_amdgcn_mfma_f32_16x16x32_bf16(
                          af[ot], bfrag, acc[ot], 0, 0, 0);

        if (kk + 1 < KK_) {          // rotate pipeline registers
            t00 = n00; t01 = n01; t10 = n10; t11 = n11;
            w00 = nw00; w01 = nw01; w10 = nw10; w11 = nw11;
        }
    }

    float* outb = out + (size_t)img * (CO_ * HW_) + hwbase + fr;
    #pragma unroll
    for (int ot = 0; ot < 4; ++ot)
        #pragma unroll
        for (int i = 0; i < 4; ++i)
            outb[(ot * 16 + fq * 4 + i) * HW_] = acc[ot][i];
}

// ---------------------------------------------------------------------------
// Fallback (R5 fused kernel) if workspace is too small for the pipeline.
// ---------------------------------------------------------------------------
#define TPF_ 128
#define NTF_ 128
__global__ __launch_bounds__(NTF_, 2) void dconv_fallback(
    const float* __restrict__ x, const float* __restrict__ w_off,
    const float* __restrict__ b_off, const float* __restrict__ w_mod,
    const float* __restrict__ b_mod, const float* __restrict__ w_reg,
    float* __restrict__ out)
{
    __shared__ short Sl[2][4][TPF_][8];
    __shared__ short Wl[2][4][CO_][8];
    const int tid = threadIdx.x;
    const int bidx = blockIdx.x & 7;
    const int hwbase = (blockIdx.x >> 3) * TPF_;
    const int hw = hwbase + tid;
    const int h = hw / W_, w = hw % W_;
    const float* xb = x + bidx * (C_ * HW_);
    float oacc[27];
    #pragma unroll
    for (int j = 0; j < 18; ++j) oacc[j] = b_off[j];
    #pragma unroll
    for (int j = 0; j < 9; ++j)  oacc[18 + j] = b_mod[j];
    for (int c = 0; c < C_; ++c) {
        float xv[9];
        #pragma unroll
        for (int t = 0; t < 9; ++t) {
            const int yy = h + t / 3 - 1, xx = w + t % 3 - 1;
            const bool ok = (yy >= 0) & (yy < H_) & (xx >= 0) & (xx < W_);
            xv[t] = ok ? xb[c * HW_ + yy * W_ + xx] : 0.0f;
        }
        const float* wo = w_off + c * 9;
        #pragma unroll
        for (int j = 0; j < 18; ++j)
            #pragma unroll
            for (int t = 0; t < 9; ++t)
                oacc[j] = fmaf(wo[j * (C_ * 9) + t], xv[t], oacc[j]);
        const float* wm = w_mod + c * 9;
        #pragma unroll
        for (int j = 0; j < 9; ++j)
            #pragma unroll
            for (int t = 0; t < 9; ++t)
                oacc[18 + j] = fmaf(wm[j * (C_ * 9) + t], xv[t], oacc[18 + j]);
    }
    #pragma unroll
    for (int j = 0; j < 18; ++j) oacc[j] = fminf(fmaxf(oacc[j], -32.0f), 32.0f);
    #pragma unroll
    for (int j = 0; j < 9; ++j)  oacc[18 + j] = 2.0f / (1.0f + expf(-oacc[18 + j]));
    auto GATHER = [&](int kk2, float* sarr) {
        const int ky = kk2 / 3, kx = kk2 % 3;
        const float py = oacc[kk2 * 2] + (float)(h - 1 + ky);
        const float px = oacc[kk2 * 2 + 1] + (float)(w - 1 + kx);
        const float m = oacc[18 + kk2];
        const float y0f = floorf(py), x0f = floorf(px);
        const float dy = py - y0f, dx = px - x0f;
        const int y0 = (int)y0f, x0 = (int)x0f, y1 = y0 + 1, x1 = x0 + 1;
        const bool vy0 = (y0 >= 0) & (y0 < H_), vy1 = (y1 >= 0) & (y1 < H_);
        const bool vx0 = (x0 >= 0) & (x0 < W_), vx1 = (x1 >= 0) & (x1 < W_);
        const float wm00 = (vy0 & vx0) ? (1.0f - dy) * (1.0f - dx) * m : 0.0f;
        const float wm01 = (vy0 & vx1) ? (1.0f - dy) * dx * m : 0.0f;
        const float wm10 = (vy1 & vx0) ? dy * (1.0f - dx) * m : 0.0f;
        const float wm11 = (vy1 & vx1) ? dy * dx * m : 0.0f;
        const int y0c = min(max(y0, 0), H_ - 1), y1c = min(max(y1, 0), H_ - 1);
        const int x0c = min(max(x0, 0), W_ - 1), x1c = min(max(x1, 0), W_ - 1);
        const int i00 = y0c * W_ + x0c, i01 = y0c * W_ + x1c;
        const int i10 = y1c * W_ + x0c, i11 = y1c * W_ + x1c;
        #pragma unroll
        for (int c4 = 0; c4 < C_; c4 += 4)
            #pragma unroll
            for (int u = 0; u < 4; ++u) {
                const float* xc = xb + (c4 + u) * HW_;
                sarr[c4 + u] = wm00 * xc[i00] + wm01 * xc[i01]
                             + wm10 * xc[i10] + wm11 * xc[i11];
            }
    };
    auto WSTAGE = [&](int kk2, s16x8* wv) {
        #pragma unroll
        for (int i = 0; i < 2; ++i) {
            const int v = i * NTF_ + tid;
            const int kg = v >> 6, o = v & 63;
            s16x8 t;
            #pragma unroll
            for (int j = 0; j < 8; ++j)
                t[j] = bf16b(w_reg[(o * C_ + kg * 8 + j) * 9 + kk2]);
            wv[i] = t;
        }
    };
    auto PACK = [&](int buf, const float* sarr, const s16x8* wv) {
        #pragma unroll
        for (int kg = 0; kg < 4; ++kg) {
            s16x8 v;
            #pragma unroll
            for (int j = 0; j < 8; ++j) v[j] = bf16b(sarr[kg * 8 + j]);
            *(s16x8*)&Sl[buf][kg][tid][0] = v;
        }
        #pragma unroll
        for (int i = 0; i < 2; ++i) {
            const int v = i * NTF_ + tid;
            const int kg = v >> 6, o = v & 63;
            *(s16x8*)&Wl[buf][kg][o][0] = wv[i];
        }
    };
    { float s0[C_]; s16x8 wv0[2]; GATHER(0, s0); WSTAGE(0, wv0); PACK(0, s0, wv0); }
    __syncthreads();
    const int lane = tid & 63, wid = tid >> 6, fr = lane & 15, fq = lane >> 4;
    f32x4 acc[4][4];
    #pragma unroll
    for (int ot = 0; ot < 4; ++ot)
        #pragma unroll
        for (int pt = 0; pt < 4; ++pt) acc[ot][pt] = (f32x4){0.f,0.f,0.f,0.f};
    #pragma unroll
    for (int kk = 0; kk < KK_; ++kk) {
        const int cur = kk & 1, nxt = cur ^ 1;
        s16x8 af[4], bfg[4];
        #pragma unroll
        for (int ot = 0; ot < 4; ++ot) af[ot] = *(const s16x8*)&Wl[cur][fq][ot*16+fr][0];
        #pragma unroll
        for (int pt = 0; pt < 4; ++pt) bfg[pt] = *(const s16x8*)&Sl[cur][fq][wid*64+pt*16+fr][0];
        float sn[C_]; s16x8 wvn[2];
        if (kk + 1 < KK_) { GATHER(kk + 1, sn); WSTAGE(kk + 1, wvn); }
        #pragma unroll
        for (int ot = 0; ot < 4; ++ot)
            #pragma unroll
            for (int pt = 0; pt < 4; ++pt)
                acc[ot][pt] = __builtin_amdgcn_mfma_f32_16x16x32_bf16(af[ot], bfg[pt], acc[ot][pt], 0, 0, 0);
        if (kk + 1 < KK_) { PACK(nxt, sn, wvn); __syncthreads(); }
    }
    float* outb = out + (size_t)bidx * (CO_ * HW_) + hwbase;
    #pragma unroll
    for (int ot = 0; ot < 4; ++ot)
        #pragma unroll
        for (int j = 0; j < 4; ++j) {
            const int o = ot * 16 + fq * 4 + j;
            float* row = outb + o * HW_ + wid * 64 + fr;
            #pragma unroll
            for (int pt = 0; pt < 4; ++pt) row[pt * 16] = acc[ot][pt][j];
        }
}

extern "C" void kernel_launch(void* const* d_in, const int* in_sizes, int n_in,
                              void* d_out, int out_size, void* d_ws, size_t ws_size,
                              hipStream_t stream) {
    const float* x     = (const float*)d_in[0];
    const float* w_off = (const float*)d_in[1];
    const float* b_off = (const float*)d_in[2];
    const float* w_mod = (const float*)d_in[3];
    const float* b_mod = (const float*)d_in[4];
    const float* w_reg = (const float*)d_in[5];
    float* out = (float*)d_out;

    const size_t WOF_OFFS = 36864;                                  // after wb
    const size_t XT_OFFS  = 65536;
    const size_t XT_BYTES = (size_t)B_ * HW_ * C_ * sizeof(short);  // 8.4 MB

    if (ws_size >= XT_OFFS + XT_BYTES) {
        short* wb  = (short*)d_ws;
        short* wof = (short*)((char*)d_ws + WOF_OFFS);
        short* xtp = (short*)((char*)d_ws + XT_OFFS);
        prep_all<<<620, 256, 0, stream>>>(x, w_reg, w_off, w_mod, xtp, wb, wof);
        dconv_fused2<<<B_ * HW_ / 128, 512, 0, stream>>>(xtp, b_off, b_mod,
                                                         wof, wb, out);
    } else {
        dconv_fallback<<<B_ * HW_ / TPF_, NTF_, 0, stream>>>(
            x, w_off, b_off, w_mod, b_mod, w_reg, out);
    }
}

// Round 16
// 46.829 us; speedup vs baseline: 1.2268x; 1.0074x over previous
//
#include <hip/hip_runtime.h>
#include <hip/hip_bf16.h>

#define B_  8
#define C_  32
#define H_  128
#define W_  128
#define CO_ 64
#define KK_ 9
#define HW_ (H_*W_)

typedef short    s16x8 __attribute__((ext_vector_type(8)));   // raw 16-bit x8
typedef _Float16 f16x8 __attribute__((ext_vector_type(8)));   // MFMA f16 frag
typedef _Float16 f16x2 __attribute__((ext_vector_type(2)));
typedef float    f32x4 __attribute__((ext_vector_type(4)));   // MFMA acc

__device__ __forceinline__ short f16b(float f) {
    _Float16 h = (_Float16)f;
    return __builtin_bit_cast(short, h);
}
__device__ __forceinline__ float h2f(short s) {
    return (float)__builtin_bit_cast(_Float16, s);   // -> v_fma_mix fodder
}
__device__ __forceinline__ short bf16b(float f) {
    __hip_bfloat16 h = __float2bfloat16(f);
    return __builtin_bit_cast(short, h);
}

// ---------------------------------------------------------------------------
// Prep (single launch, blockIdx-range dispatch). ALL f16 now:
//   blocks [0,512):   x f32[img][32][HW] -> xt f16[img][HW][32]
//   blocks [512,584): w_reg -> f16 A-frag wb[kk][kg][o(64)][j]
//   blocks [584,620): w_off||w_mod||0 -> f16 A-frag wof[kk][kg][row(32)][j]
// ---------------------------------------------------------------------------
__global__ __launch_bounds__(256) void prep_all(
    const float* __restrict__ x,
    const float* __restrict__ w_reg,
    const float* __restrict__ w_off,
    const float* __restrict__ w_mod,
    short* __restrict__ xt,
    short* __restrict__ wb,
    short* __restrict__ wof)
{
    const int bid = blockIdx.x;
    const int tid = threadIdx.x;
    if (bid < 512) {                       // ---- xt transpose
        const int img = bid & 7;
        const int pix = (bid >> 3) * 256 + tid;
        const float* xb = x + img * (C_ * HW_);
        short v[C_];
        #pragma unroll
        for (int c = 0; c < C_; ++c) v[c] = f16b(xb[c * HW_ + pix]);
        short* dst = xt + ((size_t)img * HW_ + pix) * C_;
        #pragma unroll
        for (int q = 0; q < 4; ++q)
            *(s16x8*)(dst + q * 8) = *(s16x8*)&v[q * 8];
    } else if (bid < 512 + 72) {           // ---- wb (18432 elements)
        const int idx = (bid - 512) * 256 + tid;
        const int j  = idx & 7;
        const int o  = (idx >> 3) & 63;
        const int kg = (idx >> 9) & 3;
        const int kk = idx >> 11;
        wb[idx] = f16b(w_reg[(o * C_ + kg * 8 + j) * 9 + kk]);
    } else {                               // ---- wof (9216 elements)
        const int idx = (bid - 584) * 256 + tid;
        const int j   = idx & 7;
        const int row = (idx >> 3) & 31;
        const int kg  = (idx >> 8) & 3;
        const int kk  = idx >> 10;
        const int c   = kg * 8 + j;
        float v = 0.0f;
        if (row < 18)      v = w_off[(row * C_ + c) * 9 + kk];
        else if (row < 27) v = w_mod[((row - 18) * C_ + c) * 9 + kk];
        wof[idx] = f16b(v);
    }
}

// ---------------------------------------------------------------------------
// Fused, 512-thread blocks (8 waves, 128 px). f16 data path: taps consumed
// via v_fma_mix (no unpack shifts), s packed via cvt_pkrtz, f16 MFMA.
// Phase 1: offsets via MFMA. Phase 2: gather + bilinear + einsum.
// ---------------------------------------------------------------------------
__global__ __launch_bounds__(512, 4) void dconv_fused2(
    const short* __restrict__ xt,
    const float* __restrict__ b_off,
    const float* __restrict__ b_mod,
    const short* __restrict__ wof,
    const short* __restrict__ wb,
    float* __restrict__ out)
{
    __shared__ float OFFl[27][136];            // 128 cols + pad, 14.7 KB
    __shared__ short wbl[(KK_ * 4 * 65) * 8];  // 36.6 KB, padded stride 65

    const int tid  = threadIdx.x;
    const int lane = tid & 63;
    const int wid  = tid >> 6;          // 8 waves
    const int fr   = lane & 15;         // pixel within wave slice
    const int fq   = lane >> 4;         // channel group
    const int img  = blockIdx.x & 7;    // image == XCD
    const int hwbase = (blockIdx.x >> 3) * 128 + wid * 16;
    const int hw = hwbase + fr;
    const int h  = hw / W_;
    const int w  = hw % W_;
    const short* xtb = xt + (size_t)img * HW_ * C_;
    const f16x8* wofv = (const f16x8*)wof;
    const int col = wid * 16 + fr;      // my pixel's column in OFFl (0..127)

    // ---- stage wb -> LDS (overlaps phase 1; barrier below covers it) ------
    {
        const s16x8* wbg = (const s16x8*)wb;
        s16x8* wblv = (s16x8*)wbl;
        #pragma unroll
        for (int i = 0; i < 5; ++i) {
            const int v = tid + i * 512;          // 0..2303
            if (v < KK_ * 4 * 64) {
                const int kf = v >> 6, slot = v & 63; // kf = kk*4+fq
                wblv[kf * 65 + slot] = wbg[v];
            }
        }
    }

    // ---------------- phase 1: offsets/mask via f16 MFMA -------------------
    {
        f32x4 oa0 = (f32x4){0.f, 0.f, 0.f, 0.f};
        f32x4 oa1 = (f32x4){0.f, 0.f, 0.f, 0.f};
        const f16x8 zf = (f16x8){0,0,0,0,0,0,0,0};

        #pragma unroll
        for (int t = 0; t < 9; ++t) {
            const int yy = h + t / 3 - 1;
            const int xx = w + t % 3 - 1;
            const bool ok = (yy >= 0) & (yy < H_) & (xx >= 0) & (xx < W_);
            const int idx = yy * W_ + xx;
            const f16x8 bfrag = ok ? *(const f16x8*)&xtb[idx * C_ + fq * 8] : zf;
            const f16x8 af0 = wofv[(t * 4 + fq) * 32 + fr];
            const f16x8 af1 = wofv[(t * 4 + fq) * 32 + 16 + fr];
            oa0 = __builtin_amdgcn_mfma_f32_16x16x32_f16(af0, bfrag, oa0, 0, 0, 0);
            oa1 = __builtin_amdgcn_mfma_f32_16x16x32_f16(af1, bfrag, oa1, 0, 0, 0);
        }
        // D lane l: row o = ot*16 + fq*4 + i, col = fr -> LDS
        #pragma unroll
        for (int i = 0; i < 4; ++i) {
            const int o = fq * 4 + i;                 // 0..15: offsets
            OFFl[o][col] = fminf(fmaxf(oa0[i] + b_off[o], -32.0f), 32.0f);
        }
        #pragma unroll
        for (int i = 0; i < 4; ++i) {
            const int o = 16 + fq * 4 + i;            // 16,17: off; 18..26: mask
            const float v = oa1[i];
            if (o < 18)
                OFFl[o][col] = fminf(fmaxf(v + b_off[o], -32.0f), 32.0f);
            else if (o < 27)
                OFFl[o][col] = 2.0f / (1.0f + expf(-(v + b_mod[o - 18])));
        }
    }
    __syncthreads();

    // ---------------- phase 2: gather + bilinear(f16 mix) + einsum ---------
    const short* xtg = xtb + fq * 8;
    const f16x8* wblv = (const f16x8*)wbl;

    auto WCALC = [&](int kk2, float& w00, float& w01, float& w10, float& w11,
                     int& a00, int& a01, int& a10, int& a11) {
        const int ky = kk2 / 3, kx = kk2 % 3;
        const float offy = OFFl[2 * kk2 + 0][col];
        const float offx = OFFl[2 * kk2 + 1][col];
        const float m    = OFFl[18 + kk2][col];

        const float py = offy + (float)(h - 1 + ky);
        const float px = offx + (float)(w - 1 + kx);
        const float y0f = floorf(py), x0f = floorf(px);
        const float dy = py - y0f,   dx = px - x0f;
        const int y0 = (int)y0f, x0 = (int)x0f;
        const int y1 = y0 + 1,   x1 = x0 + 1;
        const bool vy0 = (y0 >= 0) & (y0 < H_);
        const bool vy1 = (y1 >= 0) & (y1 < H_);
        const bool vx0 = (x0 >= 0) & (x0 < W_);
        const bool vx1 = (x1 >= 0) & (x1 < W_);
        w00 = (vy0 & vx0) ? (1.0f - dy) * (1.0f - dx) * m : 0.0f;
        w01 = (vy0 & vx1) ? (1.0f - dy) * dx * m         : 0.0f;
        w10 = (vy1 & vx0) ? dy * (1.0f - dx) * m         : 0.0f;
        w11 = (vy1 & vx1) ? dy * dx * m                  : 0.0f;
        const int y0c = min(max(y0, 0), H_ - 1), y1c = min(max(y1, 0), H_ - 1);
        const int x0c = min(max(x0, 0), W_ - 1), x1c = min(max(x1, 0), W_ - 1);
        a00 = (y0c * W_ + x0c) * C_;
        a01 = (y0c * W_ + x1c) * C_;
        a10 = (y1c * W_ + x0c) * C_;
        a11 = (y1c * W_ + x1c) * C_;
    };

    f32x4 acc[4];
    #pragma unroll
    for (int ot = 0; ot < 4; ++ot) acc[ot] = (f32x4){0.f, 0.f, 0.f, 0.f};

    // prologue: weights+loads for kk=0
    float w00, w01, w10, w11;
    int   a00, a01, a10, a11;
    WCALC(0, w00, w01, w10, w11, a00, a01, a10, a11);
    s16x8 t00 = *(const s16x8*)&xtg[a00];
    s16x8 t01 = *(const s16x8*)&xtg[a01];
    s16x8 t10 = *(const s16x8*)&xtg[a10];
    s16x8 t11 = *(const s16x8*)&xtg[a11];

    #pragma unroll
    for (int kk = 0; kk < KK_; ++kk) {
        // issue kk+1's weight calc + tap loads first (hide under kk's work)
        float nw00, nw01, nw10, nw11;
        s16x8 n00, n01, n10, n11;
        if (kk + 1 < KK_) {
            int b00, b01, b10, b11;
            WCALC(kk + 1, nw00, nw01, nw10, nw11, b00, b01, b10, b11);
            n00 = *(const s16x8*)&xtg[b00];
            n01 = *(const s16x8*)&xtg[b01];
            n10 = *(const s16x8*)&xtg[b10];
            n11 = *(const s16x8*)&xtg[b11];
        }

        // bilinear via f16->f32 fma (v_fma_mix: no unpack shifts)
        float sv[8];
        #pragma unroll
        for (int j = 0; j < 8; ++j) {
            float s = h2f(t00[j]) * w00;
            s = fmaf(h2f(t01[j]), w01, s);
            s = fmaf(h2f(t10[j]), w10, s);
            s = fmaf(h2f(t11[j]), w11, s);
            sv[j] = s;
        }
        // pack 2-at-a-time: v_cvt_pkrtz_f16_f32 (bit_cast: builtin returns
        // __fp16x2, our f16x2 is _Float16x2 — same bits)
        f16x8 bfrag;
        #pragma unroll
        for (int jj = 0; jj < 4; ++jj) {
            f16x2 p = __builtin_bit_cast(f16x2,
                __builtin_amdgcn_cvt_pkrtz(sv[2 * jj], sv[2 * jj + 1]));
            bfrag[2 * jj]     = p[0];
            bfrag[2 * jj + 1] = p[1];
        }

        // A-fragments from LDS (ds_read_b128)
        f16x8 af[4];
        #pragma unroll
        for (int ot = 0; ot < 4; ++ot)
            af[ot] = wblv[(kk * 4 + fq) * 65 + ot * 16 + fr];

        #pragma unroll
        for (int ot = 0; ot < 4; ++ot)
            acc[ot] = __builtin_amdgcn_mfma_f32_16x16x32_f16(
                          af[ot], bfrag, acc[ot], 0, 0, 0);

        if (kk + 1 < KK_) {          // rotate pipeline registers
            t00 = n00; t01 = n01; t10 = n10; t11 = n11;
            w00 = nw00; w01 = nw01; w10 = nw10; w11 = nw11;
        }
    }

    float* outb = out + (size_t)img * (CO_ * HW_) + hwbase + fr;
    #pragma unroll
    for (int ot = 0; ot < 4; ++ot)
        #pragma unroll
        for (int i = 0; i < 4; ++i)
            outb[(ot * 16 + fq * 4 + i) * HW_] = acc[ot][i];
}

// ---------------------------------------------------------------------------
// Fallback (R5 fused kernel, bf16) if workspace is too small.
// ---------------------------------------------------------------------------
#define TPF_ 128
#define NTF_ 128
typedef short s16x8b __attribute__((ext_vector_type(8)));
__global__ __launch_bounds__(NTF_, 2) void dconv_fallback(
    const float* __restrict__ x, const float* __restrict__ w_off,
    const float* __restrict__ b_off, const float* __restrict__ w_mod,
    const float* __restrict__ b_mod, const float* __restrict__ w_reg,
    float* __restrict__ out)
{
    __shared__ short Sl[2][4][TPF_][8];
    __shared__ short Wl[2][4][CO_][8];
    const int tid = threadIdx.x;
    const int bidx = blockIdx.x & 7;
    const int hwbase = (blockIdx.x >> 3) * TPF_;
    const int hw = hwbase + tid;
    const int h = hw / W_, w = hw % W_;
    const float* xb = x + bidx * (C_ * HW_);
    float oacc[27];
    #pragma unroll
    for (int j = 0; j < 18; ++j) oacc[j] = b_off[j];
    #pragma unroll
    for (int j = 0; j < 9; ++j)  oacc[18 + j] = b_mod[j];
    for (int c = 0; c < C_; ++c) {
        float xv[9];
        #pragma unroll
        for (int t = 0; t < 9; ++t) {
            const int yy = h + t / 3 - 1, xx = w + t % 3 - 1;
            const bool ok = (yy >= 0) & (yy < H_) & (xx >= 0) & (xx < W_);
            xv[t] = ok ? xb[c * HW_ + yy * W_ + xx] : 0.0f;
        }
        const float* wo = w_off + c * 9;
        #pragma unroll
        for (int j = 0; j < 18; ++j)
            #pragma unroll
            for (int t = 0; t < 9; ++t)
                oacc[j] = fmaf(wo[j * (C_ * 9) + t], xv[t], oacc[j]);
        const float* wm = w_mod + c * 9;
        #pragma unroll
        for (int j = 0; j < 9; ++j)
            #pragma unroll
            for (int t = 0; t < 9; ++t)
                oacc[18 + j] = fmaf(wm[j * (C_ * 9) + t], xv[t], oacc[18 + j]);
    }
    #pragma unroll
    for (int j = 0; j < 18; ++j) oacc[j] = fminf(fmaxf(oacc[j], -32.0f), 32.0f);
    #pragma unroll
    for (int j = 0; j < 9; ++j)  oacc[18 + j] = 2.0f / (1.0f + expf(-oacc[18 + j]));
    auto GATHER = [&](int kk2, float* sarr) {
        const int ky = kk2 / 3, kx = kk2 % 3;
        const float py = oacc[kk2 * 2] + (float)(h - 1 + ky);
        const float px = oacc[kk2 * 2 + 1] + (float)(w - 1 + kx);
        const float m = oacc[18 + kk2];
        const float y0f = floorf(py), x0f = floorf(px);
        const float dy = py - y0f, dx = px - x0f;
        const int y0 = (int)y0f, x0 = (int)x0f, y1 = y0 + 1, x1 = x0 + 1;
        const bool vy0 = (y0 >= 0) & (y0 < H_), vy1 = (y1 >= 0) & (y1 < H_);
        const bool vx0 = (x0 >= 0) & (x0 < W_), vx1 = (x1 >= 0) & (x1 < W_);
        const float wm00 = (vy0 & vx0) ? (1.0f - dy) * (1.0f - dx) * m : 0.0f;
        const float wm01 = (vy0 & vx1) ? (1.0f - dy) * dx * m : 0.0f;
        const float wm10 = (vy1 & vx0) ? dy * (1.0f - dx) * m : 0.0f;
        const float wm11 = (vy1 & vx1) ? dy * dx * m : 0.0f;
        const int y0c = min(max(y0, 0), H_ - 1), y1c = min(max(y1, 0), H_ - 1);
        const int x0c = min(max(x0, 0), W_ - 1), x1c = min(max(x1, 0), W_ - 1);
        const int i00 = y0c * W_ + x0c, i01 = y0c * W_ + x1c;
        const int i10 = y1c * W_ + x0c, i11 = y1c * W_ + x1c;
        #pragma unroll
        for (int c4 = 0; c4 < C_; c4 += 4)
            #pragma unroll
            for (int u = 0; u < 4; ++u) {
                const float* xc = xb + (c4 + u) * HW_;
                sarr[c4 + u] = wm00 * xc[i00] + wm01 * xc[i01]
                             + wm10 * xc[i10] + wm11 * xc[i11];
            }
    };
    auto WSTAGE = [&](int kk2, s16x8b* wv) {
        #pragma unroll
        for (int i = 0; i < 2; ++i) {
            const int v = i * NTF_ + tid;
            const int kg = v >> 6, o = v & 63;
            s16x8b t;
            #pragma unroll
            for (int j = 0; j < 8; ++j)
                t[j] = bf16b(w_reg[(o * C_ + kg * 8 + j) * 9 + kk2]);
            wv[i] = t;
        }
    };
    auto PACK = [&](int buf, const float* sarr, const s16x8b* wv) {
        #pragma unroll
        for (int kg = 0; kg < 4; ++kg) {
            s16x8b v;
            #pragma unroll
            for (int j = 0; j < 8; ++j) v[j] = bf16b(sarr[kg * 8 + j]);
            *(s16x8b*)&Sl[buf][kg][tid][0] = v;
        }
        #pragma unroll
        for (int i = 0; i < 2; ++i) {
            const int v = i * NTF_ + tid;
            const int kg = v >> 6, o = v & 63;
            *(s16x8b*)&Wl[buf][kg][o][0] = wv[i];
        }
    };
    { float s0[C_]; s16x8b wv0[2]; GATHER(0, s0); WSTAGE(0, wv0); PACK(0, s0, wv0); }
    __syncthreads();
    const int lane = tid & 63, wid = tid >> 6, fr = lane & 15, fq = lane >> 4;
    f32x4 acc[4][4];
    #pragma unroll
    for (int ot = 0; ot < 4; ++ot)
        #pragma unroll
        for (int pt = 0; pt < 4; ++pt) acc[ot][pt] = (f32x4){0.f,0.f,0.f,0.f};
    #pragma unroll
    for (int kk = 0; kk < KK_; ++kk) {
        const int cur = kk & 1, nxt = cur ^ 1;
        s16x8b af[4], bfg[4];
        #pragma unroll
        for (int ot = 0; ot < 4; ++ot) af[ot] = *(const s16x8b*)&Wl[cur][fq][ot*16+fr][0];
        #pragma unroll
        for (int pt = 0; pt < 4; ++pt) bfg[pt] = *(const s16x8b*)&Sl[cur][fq][wid*64+pt*16+fr][0];
        float sn[C_]; s16x8b wvn[2];
        if (kk + 1 < KK_) { GATHER(kk + 1, sn); WSTAGE(kk + 1, wvn); }
        #pragma unroll
        for (int ot = 0; ot < 4; ++ot)
            #pragma unroll
            for (int pt = 0; pt < 4; ++pt)
                acc[ot][pt] = __builtin_amdgcn_mfma_f32_16x16x32_bf16(af[ot], bfg[pt], acc[ot][pt], 0, 0, 0);
        if (kk + 1 < KK_) { PACK(nxt, sn, wvn); __syncthreads(); }
    }
    float* outb = out + (size_t)bidx * (CO_ * HW_) + hwbase;
    #pragma unroll
    for (int ot = 0; ot < 4; ++ot)
        #pragma unroll
        for (int j = 0; j < 4; ++j) {
            const int o = ot * 16 + fq * 4 + j;
            float* row = outb + o * HW_ + wid * 64 + fr;
            #pragma unroll
            for (int pt = 0; pt < 4; ++pt) row[pt * 16] = acc[ot][pt][j];
        }
}

extern "C" void kernel_launch(void* const* d_in, const int* in_sizes, int n_in,
                              void* d_out, int out_size, void* d_ws, size_t ws_size,
                              hipStream_t stream) {
    const float* x     = (const float*)d_in[0];
    const float* w_off = (const float*)d_in[1];
    const float* b_off = (const float*)d_in[2];
    const float* w_mod = (const float*)d_in[3];
    const float* b_mod = (const float*)d_in[4];
    const float* w_reg = (const float*)d_in[5];
    float* out = (float*)d_out;

    const size_t WOF_OFFS = 36864;                                  // after wb
    const size_t XT_OFFS  = 65536;
    const size_t XT_BYTES = (size_t)B_ * HW_ * C_ * sizeof(short);  // 8.4 MB

    if (ws_size >= XT_OFFS + XT_BYTES) {
        short* wb  = (short*)d_ws;
        short* wof = (short*)((char*)d_ws + WOF_OFFS);
        short* xtp = (short*)((char*)d_ws + XT_OFFS);
        prep_all<<<620, 256, 0, stream>>>(x, w_reg, w_off, w_mod, xtp, wb, wof);
        dconv_fused2<<<B_ * HW_ / 128, 512, 0, stream>>>(xtp, b_off, b_mod,
                                                         wof, wb, out);
    } else {
        dconv_fallback<<<B_ * HW_ / TPF_, NTF_, 0, stream>>>(
            x, w_off, b_off, w_mod, b_mod, w_reg, out);
    }
}

// Round 17
// 46.771 us; speedup vs baseline: 1.2283x; 1.0012x over previous
//
#include <hip/hip_runtime.h>
#include <hip/hip_bf16.h>

#define B_  8
#define C_  32
#define H_  128
#define W_  128
#define CO_ 64
#define KK_ 9
#define HW_ (H_*W_)

typedef short    s16x8 __attribute__((ext_vector_type(8)));   // raw 16-bit x8
typedef _Float16 f16x8 __attribute__((ext_vector_type(8)));   // MFMA f16 frag
typedef float    f32x4 __attribute__((ext_vector_type(4)));   // MFMA acc

__device__ __forceinline__ short f16b(float f) {
    _Float16 h = (_Float16)f;
    return __builtin_bit_cast(short, h);
}
__device__ __forceinline__ short bf16b(float f) {
    __hip_bfloat16 h = __float2bfloat16(f);
    return __builtin_bit_cast(short, h);
}
__device__ __forceinline__ f16x8 splat8(_Float16 v) {
    return (f16x8){v, v, v, v, v, v, v, v};
}

// ---------------------------------------------------------------------------
// Prep (single launch, blockIdx-range dispatch). ALL f16:
//   blocks [0,512):   x f32[img][32][HW] -> xt f16[img][HW][32]
//   blocks [512,584): w_reg -> f16 A-frag wb[kk][kg][o(64)][j]
//   blocks [584,620): w_off||w_mod||0 -> f16 A-frag wof[kk][kg][row(32)][j]
// ---------------------------------------------------------------------------
__global__ __launch_bounds__(256) void prep_all(
    const float* __restrict__ x,
    const float* __restrict__ w_reg,
    const float* __restrict__ w_off,
    const float* __restrict__ w_mod,
    short* __restrict__ xt,
    short* __restrict__ wb,
    short* __restrict__ wof)
{
    const int bid = blockIdx.x;
    const int tid = threadIdx.x;
    if (bid < 512) {                       // ---- xt transpose
        const int img = bid & 7;
        const int pix = (bid >> 3) * 256 + tid;
        const float* xb = x + img * (C_ * HW_);
        short v[C_];
        #pragma unroll
        for (int c = 0; c < C_; ++c) v[c] = f16b(xb[c * HW_ + pix]);
        short* dst = xt + ((size_t)img * HW_ + pix) * C_;
        #pragma unroll
        for (int q = 0; q < 4; ++q)
            *(s16x8*)(dst + q * 8) = *(s16x8*)&v[q * 8];
    } else if (bid < 512 + 72) {           // ---- wb (18432 elements)
        const int idx = (bid - 512) * 256 + tid;
        const int j  = idx & 7;
        const int o  = (idx >> 3) & 63;
        const int kg = (idx >> 9) & 3;
        const int kk = idx >> 11;
        wb[idx] = f16b(w_reg[(o * C_ + kg * 8 + j) * 9 + kk]);
    } else {                               // ---- wof (9216 elements)
        const int idx = (bid - 584) * 256 + tid;
        const int j   = idx & 7;
        const int row = (idx >> 3) & 31;
        const int kg  = (idx >> 8) & 3;
        const int kk  = idx >> 10;
        const int c   = kg * 8 + j;
        float v = 0.0f;
        if (row < 18)      v = w_off[(row * C_ + c) * 9 + kk];
        else if (row < 27) v = w_mod[((row - 18) * C_ + c) * 9 + kk];
        wof[idx] = f16b(v);
    }
}

// ---------------------------------------------------------------------------
// Fused, 512-thread blocks (8 waves, 128 px). Packed-f16 bilinear:
// bfrag = t00*w00 + t01*w01 + t10*w10 + t11*w11 entirely in v_pk_fma_f16
// (2 ch/inst, zero f32 round-trip, zero cvt/pack). f16 MFMA both phases.
// ---------------------------------------------------------------------------
__global__ __launch_bounds__(512, 4) void dconv_fused2(
    const short* __restrict__ xt,
    const float* __restrict__ b_off,
    const float* __restrict__ b_mod,
    const short* __restrict__ wof,
    const short* __restrict__ wb,
    float* __restrict__ out)
{
    __shared__ float OFFl[27][136];            // 128 cols + pad, 14.7 KB
    __shared__ short wbl[(KK_ * 4 * 65) * 8];  // 36.6 KB, padded stride 65

    const int tid  = threadIdx.x;
    const int lane = tid & 63;
    const int wid  = tid >> 6;          // 8 waves
    const int fr   = lane & 15;         // pixel within wave slice
    const int fq   = lane >> 4;         // channel group
    const int img  = blockIdx.x & 7;    // image == XCD
    const int hwbase = (blockIdx.x >> 3) * 128 + wid * 16;
    const int hw = hwbase + fr;
    const int h  = hw / W_;
    const int w  = hw % W_;
    const short* xtb = xt + (size_t)img * HW_ * C_;
    const f16x8* wofv = (const f16x8*)wof;
    const int col = wid * 16 + fr;      // my pixel's column in OFFl (0..127)

    // ---- stage wb -> LDS (overlaps phase 1; barrier below covers it) ------
    {
        const s16x8* wbg = (const s16x8*)wb;
        s16x8* wblv = (s16x8*)wbl;
        #pragma unroll
        for (int i = 0; i < 5; ++i) {
            const int v = tid + i * 512;          // 0..2303
            if (v < KK_ * 4 * 64) {
                const int kf = v >> 6, slot = v & 63; // kf = kk*4+fq
                wblv[kf * 65 + slot] = wbg[v];
            }
        }
    }

    // ---------------- phase 1: offsets/mask via f16 MFMA -------------------
    {
        f32x4 oa0 = (f32x4){0.f, 0.f, 0.f, 0.f};
        f32x4 oa1 = (f32x4){0.f, 0.f, 0.f, 0.f};
        const f16x8 zf = (f16x8){0,0,0,0,0,0,0,0};

        #pragma unroll
        for (int t = 0; t < 9; ++t) {
            const int yy = h + t / 3 - 1;
            const int xx = w + t % 3 - 1;
            const bool ok = (yy >= 0) & (yy < H_) & (xx >= 0) & (xx < W_);
            const int idx = yy * W_ + xx;
            const f16x8 bfrag = ok ? *(const f16x8*)&xtb[idx * C_ + fq * 8] : zf;
            const f16x8 af0 = wofv[(t * 4 + fq) * 32 + fr];
            const f16x8 af1 = wofv[(t * 4 + fq) * 32 + 16 + fr];
            oa0 = __builtin_amdgcn_mfma_f32_16x16x32_f16(af0, bfrag, oa0, 0, 0, 0);
            oa1 = __builtin_amdgcn_mfma_f32_16x16x32_f16(af1, bfrag, oa1, 0, 0, 0);
        }
        // D lane l: row o = ot*16 + fq*4 + i, col = fr -> LDS
        #pragma unroll
        for (int i = 0; i < 4; ++i) {
            const int o = fq * 4 + i;                 // 0..15: offsets
            OFFl[o][col] = fminf(fmaxf(oa0[i] + b_off[o], -32.0f), 32.0f);
        }
        #pragma unroll
        for (int i = 0; i < 4; ++i) {
            const int o = 16 + fq * 4 + i;            // 16,17: off; 18..26: mask
            const float v = oa1[i];
            if (o < 18)
                OFFl[o][col] = fminf(fmaxf(v + b_off[o], -32.0f), 32.0f);
            else if (o < 27)
                OFFl[o][col] = 2.0f / (1.0f + expf(-(v + b_mod[o - 18])));
        }
    }
    __syncthreads();

    // ---------------- phase 2: gather + packed-f16 bilinear + einsum -------
    const short* xtg = xtb + fq * 8;
    const f16x8* wblv = (const f16x8*)wbl;

    auto WCALC = [&](int kk2, float& w00, float& w01, float& w10, float& w11,
                     int& a00, int& a01, int& a10, int& a11) {
        const int ky = kk2 / 3, kx = kk2 % 3;
        const float offy = OFFl[2 * kk2 + 0][col];
        const float offx = OFFl[2 * kk2 + 1][col];
        const float m    = OFFl[18 + kk2][col];

        const float py = offy + (float)(h - 1 + ky);
        const float px = offx + (float)(w - 1 + kx);
        const float y0f = floorf(py), x0f = floorf(px);
        const float dy = py - y0f,   dx = px - x0f;
        const int y0 = (int)y0f, x0 = (int)x0f;
        const int y1 = y0 + 1,   x1 = x0 + 1;
        const bool vy0 = (y0 >= 0) & (y0 < H_);
        const bool vy1 = (y1 >= 0) & (y1 < H_);
        const bool vx0 = (x0 >= 0) & (x0 < W_);
        const bool vx1 = (x1 >= 0) & (x1 < W_);
        w00 = (vy0 & vx0) ? (1.0f - dy) * (1.0f - dx) * m : 0.0f;
        w01 = (vy0 & vx1) ? (1.0f - dy) * dx * m         : 0.0f;
        w10 = (vy1 & vx0) ? dy * (1.0f - dx) * m         : 0.0f;
        w11 = (vy1 & vx1) ? dy * dx * m                  : 0.0f;
        const int y0c = min(max(y0, 0), H_ - 1), y1c = min(max(y1, 0), H_ - 1);
        const int x0c = min(max(x0, 0), W_ - 1), x1c = min(max(x1, 0), W_ - 1);
        a00 = (y0c * W_ + x0c) * C_;
        a01 = (y0c * W_ + x1c) * C_;
        a10 = (y1c * W_ + x0c) * C_;
        a11 = (y1c * W_ + x1c) * C_;
    };

    f32x4 acc[4];
    #pragma unroll
    for (int ot = 0; ot < 4; ++ot) acc[ot] = (f32x4){0.f, 0.f, 0.f, 0.f};

    // prologue: weights+loads for kk=0
    float w00, w01, w10, w11;
    int   a00, a01, a10, a11;
    WCALC(0, w00, w01, w10, w11, a00, a01, a10, a11);
    s16x8 t00 = *(const s16x8*)&xtg[a00];
    s16x8 t01 = *(const s16x8*)&xtg[a01];
    s16x8 t10 = *(const s16x8*)&xtg[a10];
    s16x8 t11 = *(const s16x8*)&xtg[a11];

    #pragma unroll
    for (int kk = 0; kk < KK_; ++kk) {
        // issue kk+1's weight calc + tap loads first (hide under kk's work)
        float nw00, nw01, nw10, nw11;
        s16x8 n00, n01, n10, n11;
        if (kk + 1 < KK_) {
            int b00, b01, b10, b11;
            WCALC(kk + 1, nw00, nw01, nw10, nw11, b00, b01, b10, b11);
            n00 = *(const s16x8*)&xtg[b00];
            n01 = *(const s16x8*)&xtg[b01];
            n10 = *(const s16x8*)&xtg[b10];
            n11 = *(const s16x8*)&xtg[b11];
        }

        // packed-f16 bilinear: 2 channels/inst (v_pk_mul/v_pk_fma_f16),
        // balanced tree, no f32 round-trip, result IS the B-fragment.
        {
            const f16x8 h00 = __builtin_bit_cast(f16x8, t00);
            const f16x8 h01 = __builtin_bit_cast(f16x8, t01);
            const f16x8 h10 = __builtin_bit_cast(f16x8, t10);
            const f16x8 h11 = __builtin_bit_cast(f16x8, t11);
            const f16x8 v00 = splat8((_Float16)w00);
            const f16x8 v01 = splat8((_Float16)w01);
            const f16x8 v10 = splat8((_Float16)w10);
            const f16x8 v11 = splat8((_Float16)w11);
            const f16x8 sA = h00 * v00 + h01 * v01;
            const f16x8 sB = h10 * v10 + h11 * v11;
            const f16x8 bfrag = sA + sB;

            // A-fragments from LDS (ds_read_b128)
            f16x8 af[4];
            #pragma unroll
            for (int ot = 0; ot < 4; ++ot)
                af[ot] = wblv[(kk * 4 + fq) * 65 + ot * 16 + fr];

            #pragma unroll
            for (int ot = 0; ot < 4; ++ot)
                acc[ot] = __builtin_amdgcn_mfma_f32_16x16x32_f16(
                              af[ot], bfrag, acc[ot], 0, 0, 0);
        }

        if (kk + 1 < KK_) {          // rotate pipeline registers
            t00 = n00; t01 = n01; t10 = n10; t11 = n11;
            w00 = nw00; w01 = nw01; w10 = nw10; w11 = nw11;
        }
    }

    float* outb = out + (size_t)img * (CO_ * HW_) + hwbase + fr;
    #pragma unroll
    for (int ot = 0; ot < 4; ++ot)
        #pragma unroll
        for (int i = 0; i < 4; ++i)
            outb[(ot * 16 + fq * 4 + i) * HW_] = acc[ot][i];
}

// ---------------------------------------------------------------------------
// Fallback (R5 fused kernel, bf16) if workspace is too small.
// ---------------------------------------------------------------------------
#define TPF_ 128
#define NTF_ 128
typedef short s16x8b __attribute__((ext_vector_type(8)));
__global__ __launch_bounds__(NTF_, 2) void dconv_fallback(
    const float* __restrict__ x, const float* __restrict__ w_off,
    const float* __restrict__ b_off, const float* __restrict__ w_mod,
    const float* __restrict__ b_mod, const float* __restrict__ w_reg,
    float* __restrict__ out)
{
    __shared__ short Sl[2][4][TPF_][8];
    __shared__ short Wl[2][4][CO_][8];
    const int tid = threadIdx.x;
    const int bidx = blockIdx.x & 7;
    const int hwbase = (blockIdx.x >> 3) * TPF_;
    const int hw = hwbase + tid;
    const int h = hw / W_, w = hw % W_;
    const float* xb = x + bidx * (C_ * HW_);
    float oacc[27];
    #pragma unroll
    for (int j = 0; j < 18; ++j) oacc[j] = b_off[j];
    #pragma unroll
    for (int j = 0; j < 9; ++j)  oacc[18 + j] = b_mod[j];
    for (int c = 0; c < C_; ++c) {
        float xv[9];
        #pragma unroll
        for (int t = 0; t < 9; ++t) {
            const int yy = h + t / 3 - 1, xx = w + t % 3 - 1;
            const bool ok = (yy >= 0) & (yy < H_) & (xx >= 0) & (xx < W_);
            xv[t] = ok ? xb[c * HW_ + yy * W_ + xx] : 0.0f;
        }
        const float* wo = w_off + c * 9;
        #pragma unroll
        for (int j = 0; j < 18; ++j)
            #pragma unroll
            for (int t = 0; t < 9; ++t)
                oacc[j] = fmaf(wo[j * (C_ * 9) + t], xv[t], oacc[j]);
        const float* wm = w_mod + c * 9;
        #pragma unroll
        for (int j = 0; j < 9; ++j)
            #pragma unroll
            for (int t = 0; t < 9; ++t)
                oacc[18 + j] = fmaf(wm[j * (C_ * 9) + t], xv[t], oacc[18 + j]);
    }
    #pragma unroll
    for (int j = 0; j < 18; ++j) oacc[j] = fminf(fmaxf(oacc[j], -32.0f), 32.0f);
    #pragma unroll
    for (int j = 0; j < 9; ++j)  oacc[18 + j] = 2.0f / (1.0f + expf(-oacc[18 + j]));
    auto GATHER = [&](int kk2, float* sarr) {
        const int ky = kk2 / 3, kx = kk2 % 3;
        const float py = oacc[kk2 * 2] + (float)(h - 1 + ky);
        const float px = oacc[kk2 * 2 + 1] + (float)(w - 1 + kx);
        const float m = oacc[18 + kk2];
        const float y0f = floorf(py), x0f = floorf(px);
        const float dy = py - y0f, dx = px - x0f;
        const int y0 = (int)y0f, x0 = (int)x0f, y1 = y0 + 1, x1 = x0 + 1;
        const bool vy0 = (y0 >= 0) & (y0 < H_), vy1 = (y1 >= 0) & (y1 < H_);
        const bool vx0 = (x0 >= 0) & (x0 < W_), vx1 = (x1 >= 0) & (x1 < W_);
        const float wm00 = (vy0 & vx0) ? (1.0f - dy) * (1.0f - dx) * m : 0.0f;
        const float wm01 = (vy0 & vx1) ? (1.0f - dy) * dx * m : 0.0f;
        const float wm10 = (vy1 & vx0) ? dy * (1.0f - dx) * m : 0.0f;
        const float wm11 = (vy1 & vx1) ? dy * dx * m : 0.0f;
        const int y0c = min(max(y0, 0), H_ - 1), y1c = min(max(y1, 0), H_ - 1);
        const int x0c = min(max(x0, 0), W_ - 1), x1c = min(max(x1, 0), W_ - 1);
        const int i00 = y0c * W_ + x0c, i01 = y0c * W_ + x1c;
        const int i10 = y1c * W_ + x0c, i11 = y1c * W_ + x1c;
        #pragma unroll
        for (int c4 = 0; c4 < C_; c4 += 4)
            #pragma unroll
            for (int u = 0; u < 4; ++u) {
                const float* xc = xb + (c4 + u) * HW_;
                sarr[c4 + u] = wm00 * xc[i00] + wm01 * xc[i01]
                             + wm10 * xc[i10] + wm11 * xc[i11];
            }
    };
    auto WSTAGE = [&](int kk2, s16x8b* wv) {
        #pragma unroll
        for (int i = 0; i < 2; ++i) {
            const int v = i * NTF_ + tid;
            const int kg = v >> 6, o = v & 63;
            s16x8b t;
            #pragma unroll
            for (int j = 0; j < 8; ++j)
                t[j] = bf16b(w_reg[(o * C_ + kg * 8 + j) * 9 + kk2]);
            wv[i] = t;
        }
    };
    auto PACK = [&](int buf, const float* sarr, const s16x8b* wv) {
        #pragma unroll
        for (int kg = 0; kg < 4; ++kg) {
            s16x8b v;
            #pragma unroll
            for (int j = 0; j < 8; ++j) v[j] = bf16b(sarr[kg * 8 + j]);
            *(s16x8b*)&Sl[buf][kg][tid][0] = v;
        }
        #pragma unroll
        for (int i = 0; i < 2; ++i) {
            const int v = i * NTF_ + tid;
            const int kg = v >> 6, o = v & 63;
            *(s16x8b*)&Wl[buf][kg][o][0] = wv[i];
        }
    };
    { float s0[C_]; s16x8b wv0[2]; GATHER(0, s0); WSTAGE(0, wv0); PACK(0, s0, wv0); }
    __syncthreads();
    const int lane = tid & 63, wid = tid >> 6, fr = lane & 15, fq = lane >> 4;
    f32x4 acc[4][4];
    #pragma unroll
    for (int ot = 0; ot < 4; ++ot)
        #pragma unroll
        for (int pt = 0; pt < 4; ++pt) acc[ot][pt] = (f32x4){0.f,0.f,0.f,0.f};
    #pragma unroll
    for (int kk = 0; kk < KK_; ++kk) {
        const int cur = kk & 1, nxt = cur ^ 1;
        s16x8b af[4], bfg[4];
        #pragma unroll
        for (int ot = 0; ot < 4; ++ot) af[ot] = *(const s16x8b*)&Wl[cur][fq][ot*16+fr][0];
        #pragma unroll
        for (int pt = 0; pt < 4; ++pt) bfg[pt] = *(const s16x8b*)&Sl[cur][fq][wid*64+pt*16+fr][0];
        float sn[C_]; s16x8b wvn[2];
        if (kk + 1 < KK_) { GATHER(kk + 1, sn); WSTAGE(kk + 1, wvn); }
        #pragma unroll
        for (int ot = 0; ot < 4; ++ot)
            #pragma unroll
            for (int pt = 0; pt < 4; ++pt)
                acc[ot][pt] = __builtin_amdgcn_mfma_f32_16x16x32_bf16(af[ot], bfg[pt], acc[ot][pt], 0, 0, 0);
        if (kk + 1 < KK_) { PACK(nxt, sn, wvn); __syncthreads(); }
    }
    float* outb = out + (size_t)bidx * (CO_ * HW_) + hwbase;
    #pragma unroll
    for (int ot = 0; ot < 4; ++ot)
        #pragma unroll
        for (int j = 0; j < 4; ++j) {
            const int o = ot * 16 + fq * 4 + j;
            float* row = outb + o * HW_ + wid * 64 + fr;
            #pragma unroll
            for (int pt = 0; pt < 4; ++pt) row[pt * 16] = acc[ot][pt][j];
        }
}

extern "C" void kernel_launch(void* const* d_in, const int* in_sizes, int n_in,
                              void* d_out, int out_size, void* d_ws, size_t ws_size,
                              hipStream_t stream) {
    const float* x     = (const float*)d_in[0];
    const float* w_off = (const float*)d_in[1];
    const float* b_off = (const float*)d_in[2];
    const float* w_mod = (const float*)d_in[3];
    const float* b_mod = (const float*)d_in[4];
    const float* w_reg = (const float*)d_in[5];
    float* out = (float*)d_out;

    const size_t WOF_OFFS = 36864;                                  // after wb
    const size_t XT_OFFS  = 65536;
    const size_t XT_BYTES = (size_t)B_ * HW_ * C_ * sizeof(short);  // 8.4 MB

    if (ws_size >= XT_OFFS + XT_BYTES) {
        short* wb  = (short*)d_ws;
        short* wof = (short*)((char*)d_ws + WOF_OFFS);
        short* xtp = (short*)((char*)d_ws + XT_OFFS);
        prep_all<<<620, 256, 0, stream>>>(x, w_reg, w_off, w_mod, xtp, wb, wof);
        dconv_fused2<<<B_ * HW_ / 128, 512, 0, stream>>>(xtp, b_off, b_mod,
                                                         wof, wb, out);
    } else {
        dconv_fallback<<<B_ * HW_ / TPF_, NTF_, 0, stream>>>(
            x, w_off, b_off, w_mod, b_mod, w_reg, out);
    }
}